// Round 11
// baseline (162.449 us; speedup 1.0000x reference)
//
#include <hip/hip_runtime.h>
#include <stdint.h>

#define NB 32
#define NN 25200
#define NN4 6300          // NN/4, exact
#define RPS 3150          // rows per key-slab (NN/8, exact)
#define TOPK 1024
#define NF 16
#define CONF 0.25f
#define IOU_T 0.45f
#define NBIN 4096
#define CAP 2048
#define KEY_BASE 0xBE800001u  // lowest possible valid key (score just above 0.25)
#define PITCH 257             // uint4 row pitch in LDS (bank-spread, no swizzle)

// monotone-ascending uint32 map of the reference's s = valid ? obj*cls : -1.0
// Valid entries (obj>CONF && score>CONF) map to keys >= KEY_BASE; all invalid
// entries (s=-1.0 -> 0x407FFFFF) land strictly below KEY_BASE.
__device__ __forceinline__ uint32_t score_key(float obj, float cls) {
  float score = __fmul_rn(cls, obj);
  bool valid = (obj > CONF) && (score > CONF);
  float s = valid ? score : -1.0f;
  uint32_t u = __float_as_uint(s);
  return (u & 0x80000000u) ? ~u : (u | 0x80000000u);
}

__device__ __forceinline__ uint64_t shfl_xor_u64(uint64_t v, int m) {
  uint32_t lo = __shfl_xor((uint32_t)v, m, 64);
  uint32_t hi = __shfl_xor((uint32_t)(v >> 32), m, 64);
  return ((uint64_t)hi << 32) | lo;
}

// R11: SINGLE fused kernel. grid (NB, 8), 1024 threads, 1 block/CU (136 KB
// LDS), all 256 blocks co-resident (proven assumption R5-R10).
// Phases, chained by the R6 release/relaxed-poll/acquire protocol:
//   0. keys: block (b,s) computes keys for rows s*3150..+3149 of image b —
//      256 blocks spread the 51.6 MB pred read across all CUs (this is NOT
//      the R8-lesson 32-block fold). release cntk[b].
//   1. select (s==0 only): spin cntk[b]==8, then the R10 k_select body with
//      LDS carved from the big buffer. Ballot/Kvec stay in LDS (no vb
//      global); n stays in registers (no sel global). Writes boxv/arv for
//      workers; release cnts[b].
//   2. mask (all): workers spin cnts[b]>=1, load boxes to LDS; BALANCED
//      mapping: block s computes row-quads i0 = 32*rg + 4*s (every block
//      gets identical work; the old contiguous slabs were 2x unbalanced and
//      slab-0 — the tail block — had the heaviest). Identical per-(i,j)
//      arithmetic. release cntm[b].
//   3. tail (s==0): early output-gather, spin cntm[b]==8, stage mask to LDS
//      (pitch-257), R10 Jacobi fixpoint, write det/keep.
// Counters are zeroed by a 384-byte hipMemsetAsync before the launch
// (stream-ordered, graph-capture-safe — the harness itself memsets).
__global__ __launch_bounds__(1024, 4) void k_nms(const float* __restrict__ pred,
                                                 uint32_t* __restrict__ keys,
                                                 float4* __restrict__ boxv,
                                                 float* __restrict__ arv,
                                                 uint32_t* __restrict__ mask,
                                                 uint32_t* __restrict__ cnt,
                                                 float* __restrict__ det,
                                                 float* __restrict__ keep_out) {
  int b = blockIdx.x;
  int sblk = blockIdx.y;
  int tid = threadIdx.x;
  int lane = tid & 63, wid = tid >> 6;
  int rg = tid & 31;
  int cc = tid >> 5;

  __shared__ uint4 sm4[32 * PITCH];      // 131.6 KB big buffer (stage target)
  __shared__ uint32_t part[1024];
  __shared__ uint32_t Kvec[32];
  __shared__ uint32_t vbs[32];
  __shared__ uint32_t sflag;
  __shared__ uint32_t wsum[16];
  __shared__ uint32_t sh_bin;
  __shared__ uint32_t sh_cnt;

  // disjoint carves inside sm4 (all dead before the stage overwrites them):
  float* bx1 = (float*)sm4;              // 5 x 4 KB box arrays   [0, 20K)
  float* by1 = bx1 + TOPK;
  float* bx2 = by1 + TOPK;
  float* by2 = bx2 + TOPK;
  float* bar = by2 + TOPK;
  uint32_t* hist = (uint32_t*)(bar + TOPK);   // 16 KB              [20K, 36K)
  uint64_t* ent = (uint64_t*)(hist + NBIN);   // 16 KB              [36K, 52K)

  uint32_t* cntk = cnt;
  uint32_t* cnts = cnt + NB;
  uint32_t* cntm = cnt + 2 * NB;

  // ---- phase 0: keys for this block's row chunk (full-grid HBM spread) ----
  {
    int base = sblk * RPS;
    #pragma unroll
    for (int q = 0; q < 4; ++q) {
      int t = tid + q * 1024;
      if (t < RPS) {
        int g = b * NN + base + t;
        const float* row = pred + (size_t)g * NF;
        keys[g] = score_key(row[4], row[15]);
      }
    }
  }
  __syncthreads();   // drain all threads' key stores (to L2)
  if (tid == 0)
    __hip_atomic_fetch_add(&cntk[b], 1u, __ATOMIC_RELEASE, __HIP_MEMORY_SCOPE_AGENT);

  int n = 0;  // slab-0: selected source row for this rank (kept in register)

  if (sblk == 0) {
    // ---- phase 1: select (R10 k_select body, LDS carved) ----
    if (tid == 0) {
      while (__hip_atomic_load(&cntk[b], __ATOMIC_RELAXED, __HIP_MEMORY_SCOPE_AGENT) < 8u)
        __builtin_amdgcn_s_sleep(16);
      (void)__hip_atomic_load(&cntk[b], __ATOMIC_ACQUIRE, __HIP_MEMORY_SCOPE_AGENT);
    }
    __syncthreads();

    const uint4* kb4 = (const uint4*)(keys + (size_t)b * NN);
    #pragma unroll
    for (int k = 0; k < 4; ++k) hist[tid + 1024 * k] = 0;
    ent[tid] = 0; ent[tid + 1024] = 0;
    if (tid == 0) { sh_cnt = 0; sh_bin = 0; }
    __syncthreads();

    // select phase 1: load keys into registers + histogram
    uint4 kreg[7];
    #pragma unroll
    for (int k = 0; k < 7; ++k) {
      int i = tid + k * 1024;
      if (i < NN4) {
        kreg[k] = kb4[i];
        uint32_t kv[4] = {kreg[k].x, kreg[k].y, kreg[k].z, kreg[k].w};
        #pragma unroll
        for (int c = 0; c < 4; ++c) {
          uint32_t key = kv[c];
          if (key >= KEY_BASE) {
            uint32_t bin = (key - KEY_BASE) >> 12;
            if (bin > NBIN - 1) bin = NBIN - 1;
            atomicAdd(&hist[bin], 1u);
          }
        }
      }
    }
    __syncthreads();

    // select phase 2: descending-bin cumulative; find crossing bin
    uint32_t h[4]; uint32_t s = 0;
    #pragma unroll
    for (int k = 0; k < 4; ++k) { h[k] = hist[NBIN - 1 - (4 * tid + k)]; s += h[k]; }
    uint32_t my = s;
    #pragma unroll
    for (int d = 1; d < 64; d <<= 1) {
      uint32_t v = __shfl_up(s, d, 64);
      if (lane >= d) s += v;
    }
    if (lane == 63) wsum[wid] = s;
    __syncthreads();
    uint32_t base = 0;
    for (int w = 0; w < wid; ++w) base += wsum[w];
    uint32_t cum = base + s - my;  // exclusive prefix (descending bins)
    #pragma unroll
    for (int k = 0; k < 4; ++k) {
      if (cum < TOPK && cum + h[k] >= TOPK) sh_bin = (uint32_t)(NBIN - 1 - (4 * tid + k));
      cum += h[k];
    }
    __syncthreads();
    uint32_t thr = KEY_BASE + (sh_bin << 12);

    // select phase 3: compact from registers
    #pragma unroll
    for (int k = 0; k < 7; ++k) {
      int i = tid + k * 1024;
      if (i < NN4) {
        uint32_t kv[4] = {kreg[k].x, kreg[k].y, kreg[k].z, kreg[k].w};
        #pragma unroll
        for (int c = 0; c < 4; ++c) {
          uint32_t key = kv[c];
          if (key >= thr) {
            uint32_t p = atomicAdd(&sh_cnt, 1u);
            if (p < CAP) ent[p] = ((uint64_t)key << 32) | (uint32_t)(~(uint32_t)(4 * i + c));
          }
        }
      }
    }
    __syncthreads();

    // select phase 4: register bitonic, 2048 descending
    uint64_t v0 = ent[tid], v1 = ent[tid + 1024];
    for (unsigned kk = 2; kk <= CAP; kk <<= 1) {
      for (unsigned j = kk >> 1; j > 0; j >>= 1) {
        if (j == 1024) {
          uint64_t mx = v0 > v1 ? v0 : v1;
          uint64_t mn = v0 > v1 ? v1 : v0;
          v0 = mx; v1 = mn;  // desc=true for kk=2048
        } else if (j >= 64) {
          __syncthreads();
          ent[tid] = v0; ent[tid + 1024] = v1;
          __syncthreads();
          uint64_t p0 = ent[tid ^ j], p1 = ent[(tid ^ j) + 1024];
          bool low = ((tid & j) == 0);
          bool d0 = ((tid & kk) == 0);
          bool d1 = (((tid + 1024) & kk) == 0);
          v0 = (low != d0) ? (v0 < p0 ? v0 : p0) : (v0 > p0 ? v0 : p0);
          v1 = (low != d1) ? (v1 < p1 ? v1 : p1) : (v1 > p1 ? v1 : p1);
        } else {
          uint64_t p0 = shfl_xor_u64(v0, (int)j);
          uint64_t p1 = shfl_xor_u64(v1, (int)j);
          bool low = ((tid & j) == 0);
          bool d0 = ((tid & kk) == 0);
          bool d1 = (((tid + 1024) & kk) == 0);
          v0 = (low != d0) ? (v0 < p0 ? v0 : p0) : (v0 > p0 ? v0 : p0);
          v1 = (low != d1) ? (v1 < p1 ? v1 : p1) : (v1 > p1 ? v1 : p1);
        }
      }
    }
    uint32_t key = (uint32_t)(v0 >> 32);
    uint32_t nn = ~(uint32_t)(v0 & 0xFFFFFFFFu);
    if (nn >= NN) nn = 0;  // zero-pad path
    n = (int)nn;

    // validity ballot straight into LDS (no global round-trip)
    bool valid = key >= KEY_BASE;
    uint64_t bal = __ballot(valid);
    if (lane == 0) {
      vbs[2 * wid] = (uint32_t)bal;  vbs[2 * wid + 1] = (uint32_t)(bal >> 32);
      Kvec[2 * wid] = (uint32_t)bal; Kvec[2 * wid + 1] = (uint32_t)(bal >> 32);
    }

    // boxes: one scattered gather; fill LDS arrays AND global (for workers)
    {
      const float4* row = (const float4*)(pred + ((size_t)b * NN + n) * NF);
      float4 r0 = row[0];
      float hw = __fmul_rn(r0.z, 0.5f), hh = __fmul_rn(r0.w, 0.5f);
      float x1 = __fsub_rn(r0.x, hw), y1 = __fsub_rn(r0.y, hh);
      float x2 = __fadd_rn(r0.x, hw), y2 = __fadd_rn(r0.y, hh);
      float ar = __fmul_rn(__fsub_rn(x2, x1), __fsub_rn(y2, y1));
      bx1[tid] = x1; by1[tid] = y1; bx2[tid] = x2; by2[tid] = y2; bar[tid] = ar;
      boxv[(size_t)b * TOPK + tid] = make_float4(x1, y1, x2, y2);
      arv[(size_t)b * TOPK + tid] = ar;
    }
    __syncthreads();   // drain boxv/arv stores + order LDS box writes
    if (tid == 0)
      __hip_atomic_fetch_add(&cnts[b], 1u, __ATOMIC_RELEASE, __HIP_MEMORY_SCOPE_AGENT);
  } else {
    // workers: wait for select, then load boxes to LDS
    if (tid == 0) {
      while (__hip_atomic_load(&cnts[b], __ATOMIC_RELAXED, __HIP_MEMORY_SCOPE_AGENT) < 1u)
        __builtin_amdgcn_s_sleep(16);
      (void)__hip_atomic_load(&cnts[b], __ATOMIC_ACQUIRE, __HIP_MEMORY_SCOPE_AGENT);
    }
    __syncthreads();
    {
      float4 bb = boxv[(size_t)b * TOPK + tid];
      bx1[tid] = bb.x; by1[tid] = bb.y; bx2[tid] = bb.z; by2[tid] = bb.w;
      bar[tid] = arv[(size_t)b * TOPK + tid];
    }
    __syncthreads();
  }

  // ---- phase 2: mask, BALANCED quad-interleaved mapping ----
  // block sblk handles row-quads i0 = 32*rg + 4*sblk; iw = i0>>5 == rg, so
  // the active-word count per (rg) is 32-rg for EVERY block -> equal work.
  int i0 = 32 * rg + 4 * sblk;    // rows i0..i0+3, all in word iw == rg
  uint32_t wreg[4] = {0u, 0u, 0u, 0u};
  if (cc >= rg) {
    float rx1[4], ry1[4], rx2[4], ry2[4], rar[4];
    #pragma unroll
    for (int k = 0; k < 4; ++k) {
      rx1[k] = bx1[i0 + k]; ry1[k] = by1[i0 + k];
      rx2[k] = bx2[i0 + k]; ry2[k] = by2[i0 + k]; rar[k] = bar[i0 + k];
    }
    for (int jj = 0; jj < 32; ++jj) {
      int j = cc * 32 + jj;
      float cx1 = bx1[j], cy1 = by1[j], cx2 = bx2[j], cy2 = by2[j], car = bar[j];
      #pragma unroll
      for (int k = 0; k < 4; ++k) {
        float lx = fmaxf(rx1[k], cx1);
        float ly = fmaxf(ry1[k], cy1);
        float rx = fminf(rx2[k], cx2);
        float ry = fminf(ry2[k], cy2);
        float wd = fmaxf(__fsub_rn(rx, lx), 0.0f);
        float ht = fmaxf(__fsub_rn(ry, ly), 0.0f);
        float inter = __fmul_rn(wd, ht);
        float den = __fadd_rn(__fsub_rn(__fadd_rn(rar[k], car), inter), 1e-7f);
        float iou = __fdiv_rn(inter, den);
        wreg[k] |= (iou > IOU_T ? 1u : 0u) << jj;
      }
    }
    if (cc == rg) {
      #pragma unroll
      for (int k = 0; k < 4; ++k)
        wreg[k] &= ~((2u << ((i0 + k) & 31)) - 1u);  // keep only j > i (strict)
    }
  }
  {
    uint4 out = make_uint4(wreg[0], wreg[1], wreg[2], wreg[3]);
    *(uint4*)&mask[((size_t)b * 32 + cc) * TOPK + i0] = out;
  }
  __syncthreads();   // drain mask stores
  if (tid == 0)
    __hip_atomic_fetch_add(&cntm[b], 1u, __ATOMIC_RELEASE, __HIP_MEMORY_SCOPE_AGENT);
  if (sblk != 0) return;

  // ---- phase 3 (sblk==0): early-gather, wait, stage, Jacobi, output ----
  const float4* rowv = (const float4*)(pred + ((size_t)b * NN + n) * NF);
  float4 r0 = rowv[0], r1 = rowv[1], r2 = rowv[2], r3 = rowv[3];

  if (tid == 0) {
    while (__hip_atomic_load(&cntm[b], __ATOMIC_RELAXED, __HIP_MEMORY_SCOPE_AGENT) < 8u)
      __builtin_amdgcn_s_sleep(16);
    (void)__hip_atomic_load(&cntm[b], __ATOMIC_ACQUIRE, __HIP_MEMORY_SCOPE_AGENT);
  }
  __syncthreads();

  // bulk stage: 128 KiB coalesced into pitch-257 LDS rows
  const uint4* gm4 = (const uint4*)(mask + (size_t)b * (32 * TOPK));
  #pragma unroll
  for (int q = 0; q < 8; ++q) {
    int idx4 = tid + q * 1024;          // uint4 index 0..8191
    int row = idx4 >> 8;                // 256 uint4 per mask word-row
    int col4 = idx4 & 255;
    sm4[row * PITCH + col4] = gm4[idx4];
  }
  __syncthreads();

  // Jacobi sweeps: K <- vb & ~S^T K until fixpoint (== exact greedy keep;
  // uniqueness by induction on smallest index, R10 derivation).
  {
    int l = tid & 31;                    // mask word this thread accumulates
    int chunk = tid >> 5;                // row block chunk*32..chunk*32+31
    const int rbase = l * PITCH + chunk * 8;
    uint32_t go = 1u;
    for (int sweep = 0; sweep < 1030 && go; ++sweep) {
      uint32_t kc = Kvec[chunk];         // kept bits for this row block
      uint32_t acc = 0;
      #pragma unroll
      for (int q = 0; q < 8; ++q) {
        uint4 v = sm4[rbase + q];
        acc |= (0u - ((kc >> (q * 4 + 0)) & 1u)) & v.x;
        acc |= (0u - ((kc >> (q * 4 + 1)) & 1u)) & v.y;
        acc |= (0u - ((kc >> (q * 4 + 2)) & 1u)) & v.z;
        acc |= (0u - ((kc >> (q * 4 + 3)) & 1u)) & v.w;
      }
      part[tid] = acc;
      __syncthreads();
      if (tid < 32) {
        uint32_t red = 0;
        #pragma unroll
        for (int c = 0; c < 32; ++c) red |= part[c * 32 + tid];
        uint32_t nk = vbs[tid] & ~red;
        uint64_t chg = __ballot(nk != Kvec[tid]);
        Kvec[tid] = nk;
        if (tid == 0) sflag = (chg != 0ull) ? 1u : 0u;
      }
      __syncthreads();
      go = sflag;
    }
  }

  // output: row already in registers (gathered before the spin)
  bool kept = (Kvec[tid >> 5] >> (tid & 31)) & 1u;
  float m = kept ? 1.0f : 0.0f;
  float score = __fmul_rn(r3.w, r1.x);   // == cls*obj, identical to reference path
  float hw = __fmul_rn(r0.z, 0.5f), hh = __fmul_rn(r0.w, 0.5f);
  float4 o0 = make_float4(__fsub_rn(r0.x, hw) * m, __fsub_rn(r0.y, hh) * m,
                          __fadd_rn(r0.x, hw) * m, __fadd_rn(r0.y, hh) * m);
  float4 o1 = make_float4(score * m, r1.y * m, r1.z * m, r1.w * m);
  float4 o2 = make_float4(r2.x * m, r2.y * m, r2.z * m, r2.w * m);
  float4 o3 = make_float4(r3.x * m, r3.y * m, r3.z * m, 0.0f);
  float4* dst = (float4*)(det + ((size_t)b * TOPK + tid) * NF);
  dst[0] = o0; dst[1] = o1; dst[2] = o2; dst[3] = o3;
  keep_out[(size_t)b * TOPK + tid] = m;
}

extern "C" void kernel_launch(void* const* d_in, const int* in_sizes, int n_in,
                              void* d_out, int out_size, void* d_ws, size_t ws_size,
                              hipStream_t stream) {
  const float* pred = (const float*)d_in[0];
  float* det = (float*)d_out;
  float* keep = det + (size_t)NB * TOPK * NF;

  uint8_t* ws = (uint8_t*)d_ws;
  size_t off = 0;
  uint32_t* keys = (uint32_t*)(ws + off); off += (size_t)NB * NN * 4;       // 3.2 MB
  float4* boxv = (float4*)(ws + off);     off += (size_t)NB * TOPK * 16;    // 512 KB
  float* arv = (float*)(ws + off);        off += (size_t)NB * TOPK * 4;     // 128 KB
  uint32_t* mask = (uint32_t*)(ws + off); off += (size_t)NB * 32 * TOPK * 4;// 4 MB
  uint32_t* cnt = (uint32_t*)(ws + off);  off += (size_t)3 * NB * 4;        // 384 B

  hipMemsetAsync(cnt, 0, (size_t)3 * NB * 4, stream);
  dim3 g(NB, 8);
  k_nms<<<g, 1024, 0, stream>>>(pred, keys, boxv, arv, mask, cnt, det, keep);
}

// Round 12
// 161.876 us; speedup vs baseline: 1.0035x; 1.0035x over previous
//
#include <hip/hip_runtime.h>
#include <stdint.h>

#define NB 32
#define NN 25200
#define NN4 6300          // NN/4, exact
#define RPS 3150          // rows per key-slab (NN/8, exact)
#define TOPK 1024
#define NF 16
#define CONF 0.25f
#define IOU_T 0.45f
#define NBIN 4096
#define CAP 2048
#define KEY_BASE 0xBE800001u  // lowest possible valid key (score just above 0.25)
#define PITCH 257             // uint4 row pitch in LDS (bank-spread, no swizzle)

// monotone-ascending uint32 map of the reference's s = valid ? obj*cls : -1.0
// Valid entries (obj>CONF && score>CONF) map to keys >= KEY_BASE; all invalid
// entries (s=-1.0 -> 0x407FFFFF) land strictly below KEY_BASE.
__device__ __forceinline__ uint32_t score_key(float obj, float cls) {
  float score = __fmul_rn(cls, obj);
  bool valid = (obj > CONF) && (score > CONF);
  float s = valid ? score : -1.0f;
  uint32_t u = __float_as_uint(s);
  return (u & 0x80000000u) ? ~u : (u | 0x80000000u);
}

__device__ __forceinline__ uint64_t shfl_xor_u64(uint64_t v, int m) {
  uint32_t lo = __shfl_xor((uint32_t)v, m, 64);
  uint32_t hi = __shfl_xor((uint32_t)(v >> 32), m, 64);
  return ((uint64_t)hi << 32) | lo;
}

// R12: single fused kernel, REDUNDANT SELECT (R11 post-mortem: the phase
// handoffs were the 105us kernel's excess — F' = 57us proved fusion's prize).
// grid (NB, 8), 1024 threads, 1 block/CU, all 256 blocks co-resident.
// Phases, chained by the R6 release/relaxed-poll/single-acquire protocol:
//   0. keys: block (b,s) computes keys for rows s*3150..+3149 of image b
//      (full-grid HBM spread). release cntk[b].
//   1. select: ALL blocks spin cntk[b]==8, then EVERY block runs the full
//      histogram+compact+bitonic select REDUNDANTLY from global keys.
//      Determinism: LDS-atomic histogram is order-invariant (sums); the
//      compaction's ticket order is erased by the bitonic total order on
//      (key, ~n) with unique n -> all 8 blocks derive IDENTICAL results.
//      This deletes the select->worker handoff (no boxv/arv globals, no
//      third counter, no second cross-L2 acquire). Boxes land in local LDS.
//   2. mask: balanced quad-interleave (block s does row-quads i0=32*rg+4*s;
//      identical work per block; per-(i,j) arithmetic unchanged). release
//      cntm[b]; workers exit.
//   3. tail (s==0): early output-gather, spin cntm[b]==8, stage mask to LDS
//      (pitch-257), Jacobi fixpoint (== exact greedy, R10), write det/keep.
// Counters zeroed by a 256-byte hipMemsetAsync (stream-ordered, capture-safe).
__global__ __launch_bounds__(1024, 4) void k_nms(const float* __restrict__ pred,
                                                 uint32_t* __restrict__ keys,
                                                 uint32_t* __restrict__ mask,
                                                 uint32_t* __restrict__ cnt,
                                                 float* __restrict__ det,
                                                 float* __restrict__ keep_out) {
  int b = blockIdx.x;
  int sblk = blockIdx.y;
  int tid = threadIdx.x;
  int lane = tid & 63, wid = tid >> 6;
  int rg = tid & 31;
  int cc = tid >> 5;

  __shared__ uint4 sm4[32 * PITCH];      // 131.6 KB big buffer (stage target)
  __shared__ uint32_t part[1024];
  __shared__ uint32_t Kvec[32];
  __shared__ uint32_t vbs[32];
  __shared__ uint32_t sflag;
  __shared__ uint32_t wsum[16];
  __shared__ uint32_t sh_bin;
  __shared__ uint32_t sh_cnt;

  // disjoint carves inside sm4 (all dead before the stage overwrites them):
  float* bx1 = (float*)sm4;              // 5 x 4 KB box arrays   [0, 20K)
  float* by1 = bx1 + TOPK;
  float* bx2 = by1 + TOPK;
  float* by2 = bx2 + TOPK;
  float* bar = by2 + TOPK;
  uint32_t* hist = (uint32_t*)(bar + TOPK);   // 16 KB              [20K, 36K)
  uint64_t* ent = (uint64_t*)(hist + NBIN);   // 16 KB              [36K, 52K)

  uint32_t* cntk = cnt;
  uint32_t* cntm = cnt + NB;

  // ---- phase 0: keys for this block's row chunk (full-grid HBM spread) ----
  {
    int base = sblk * RPS;
    #pragma unroll
    for (int q = 0; q < 4; ++q) {
      int t = tid + q * 1024;
      if (t < RPS) {
        int g = b * NN + base + t;
        const float* row = pred + (size_t)g * NF;
        keys[g] = score_key(row[4], row[15]);
      }
    }
  }
  __syncthreads();   // drain all threads' key stores
  if (tid == 0) {
    __hip_atomic_fetch_add(&cntk[b], 1u, __ATOMIC_RELEASE, __HIP_MEMORY_SCOPE_AGENT);
    // every block waits for all 8 key slabs of its image, then one acquire
    while (__hip_atomic_load(&cntk[b], __ATOMIC_RELAXED, __HIP_MEMORY_SCOPE_AGENT) < 8u)
      __builtin_amdgcn_s_sleep(16);
    (void)__hip_atomic_load(&cntk[b], __ATOMIC_ACQUIRE, __HIP_MEMORY_SCOPE_AGENT);
  }
  __syncthreads();

  // ---- phase 1: select, run REDUNDANTLY by all 8 blocks of this image ----
  const uint4* kb4 = (const uint4*)(keys + (size_t)b * NN);
  #pragma unroll
  for (int k = 0; k < 4; ++k) hist[tid + 1024 * k] = 0;
  ent[tid] = 0; ent[tid + 1024] = 0;
  if (tid == 0) { sh_cnt = 0; sh_bin = 0; }
  __syncthreads();

  // load keys into registers (single global pass) + histogram
  uint4 kreg[7];
  #pragma unroll
  for (int k = 0; k < 7; ++k) {
    int i = tid + k * 1024;
    if (i < NN4) {
      kreg[k] = kb4[i];
      uint32_t kv[4] = {kreg[k].x, kreg[k].y, kreg[k].z, kreg[k].w};
      #pragma unroll
      for (int c = 0; c < 4; ++c) {
        uint32_t key = kv[c];
        if (key >= KEY_BASE) {
          uint32_t bin = (key - KEY_BASE) >> 12;
          if (bin > NBIN - 1) bin = NBIN - 1;
          atomicAdd(&hist[bin], 1u);
        }
      }
    }
  }
  __syncthreads();

  // descending-bin cumulative via shfl scan; find crossing bin
  uint32_t h[4]; uint32_t s = 0;
  #pragma unroll
  for (int k = 0; k < 4; ++k) { h[k] = hist[NBIN - 1 - (4 * tid + k)]; s += h[k]; }
  uint32_t my = s;
  #pragma unroll
  for (int d = 1; d < 64; d <<= 1) {
    uint32_t v = __shfl_up(s, d, 64);
    if (lane >= d) s += v;
  }
  if (lane == 63) wsum[wid] = s;
  __syncthreads();
  uint32_t base = 0;
  for (int w = 0; w < wid; ++w) base += wsum[w];
  uint32_t cum = base + s - my;  // exclusive prefix (descending bins)
  #pragma unroll
  for (int k = 0; k < 4; ++k) {
    if (cum < TOPK && cum + h[k] >= TOPK) sh_bin = (uint32_t)(NBIN - 1 - (4 * tid + k));
    cum += h[k];
  }
  __syncthreads();
  uint32_t thr = KEY_BASE + (sh_bin << 12);

  // compact from registers (no second global pass)
  #pragma unroll
  for (int k = 0; k < 7; ++k) {
    int i = tid + k * 1024;
    if (i < NN4) {
      uint32_t kv[4] = {kreg[k].x, kreg[k].y, kreg[k].z, kreg[k].w};
      #pragma unroll
      for (int c = 0; c < 4; ++c) {
        uint32_t key = kv[c];
        if (key >= thr) {
          uint32_t p = atomicAdd(&sh_cnt, 1u);
          if (p < CAP) ent[p] = ((uint64_t)key << 32) | (uint32_t)(~(uint32_t)(4 * i + c));
        }
      }
    }
  }
  __syncthreads();

  // register bitonic, 2048 descending, 2 elems/thread (canonicalizes any
  // compaction arrival order -> identical results across the 8 blocks)
  uint64_t v0 = ent[tid], v1 = ent[tid + 1024];
  for (unsigned kk = 2; kk <= CAP; kk <<= 1) {
    for (unsigned j = kk >> 1; j > 0; j >>= 1) {
      if (j == 1024) {
        uint64_t mx = v0 > v1 ? v0 : v1;
        uint64_t mn = v0 > v1 ? v1 : v0;
        v0 = mx; v1 = mn;  // desc=true for kk=2048
      } else if (j >= 64) {
        __syncthreads();
        ent[tid] = v0; ent[tid + 1024] = v1;
        __syncthreads();
        uint64_t p0 = ent[tid ^ j], p1 = ent[(tid ^ j) + 1024];
        bool low = ((tid & j) == 0);
        bool d0 = ((tid & kk) == 0);
        bool d1 = (((tid + 1024) & kk) == 0);
        v0 = (low != d0) ? (v0 < p0 ? v0 : p0) : (v0 > p0 ? v0 : p0);
        v1 = (low != d1) ? (v1 < p1 ? v1 : p1) : (v1 > p1 ? v1 : p1);
      } else {
        uint64_t p0 = shfl_xor_u64(v0, (int)j);
        uint64_t p1 = shfl_xor_u64(v1, (int)j);
        bool low = ((tid & j) == 0);
        bool d0 = ((tid & kk) == 0);
        bool d1 = (((tid + 1024) & kk) == 0);
        v0 = (low != d0) ? (v0 < p0 ? v0 : p0) : (v0 > p0 ? v0 : p0);
        v1 = (low != d1) ? (v1 < p1 ? v1 : p1) : (v1 > p1 ? v1 : p1);
      }
    }
  }
  uint32_t key = (uint32_t)(v0 >> 32);
  uint32_t nn = ~(uint32_t)(v0 & 0xFFFFFFFFu);
  if (nn >= NN) nn = 0;  // zero-pad path
  int n = (int)nn;       // this rank's source row — stays in a register

  // validity ballot straight into LDS (used by the tail block only)
  {
    bool valid = key >= KEY_BASE;
    uint64_t bal = __ballot(valid);
    if (lane == 0) {
      vbs[2 * wid] = (uint32_t)bal;  vbs[2 * wid + 1] = (uint32_t)(bal >> 32);
      Kvec[2 * wid] = (uint32_t)bal; Kvec[2 * wid + 1] = (uint32_t)(bal >> 32);
    }
  }

  // boxes: one scattered gather into LOCAL LDS (no global round-trip)
  {
    const float4* row = (const float4*)(pred + ((size_t)b * NN + n) * NF);
    float4 r0 = row[0];
    float hw = __fmul_rn(r0.z, 0.5f), hh = __fmul_rn(r0.w, 0.5f);
    float x1 = __fsub_rn(r0.x, hw), y1 = __fsub_rn(r0.y, hh);
    float x2 = __fadd_rn(r0.x, hw), y2 = __fadd_rn(r0.y, hh);
    bx1[tid] = x1; by1[tid] = y1; bx2[tid] = x2; by2[tid] = y2;
    bar[tid] = __fmul_rn(__fsub_rn(x2, x1), __fsub_rn(y2, y1));
  }
  __syncthreads();

  // ---- phase 2: mask, balanced quad-interleaved mapping ----
  // block sblk handles row-quads i0 = 32*rg + 4*sblk; iw == rg for every
  // block -> per-(rg) active words = 32-rg for ALL blocks -> equal work.
  int i0 = 32 * rg + 4 * sblk;    // rows i0..i0+3, all in word iw == rg
  uint32_t wreg[4] = {0u, 0u, 0u, 0u};
  if (cc >= rg) {
    float rx1[4], ry1[4], rx2[4], ry2[4], rar[4];
    #pragma unroll
    for (int k = 0; k < 4; ++k) {
      rx1[k] = bx1[i0 + k]; ry1[k] = by1[i0 + k];
      rx2[k] = bx2[i0 + k]; ry2[k] = by2[i0 + k]; rar[k] = bar[i0 + k];
    }
    for (int jj = 0; jj < 32; ++jj) {
      int j = cc * 32 + jj;
      float cx1 = bx1[j], cy1 = by1[j], cx2 = bx2[j], cy2 = by2[j], car = bar[j];
      #pragma unroll
      for (int k = 0; k < 4; ++k) {
        float lx = fmaxf(rx1[k], cx1);
        float ly = fmaxf(ry1[k], cy1);
        float rx = fminf(rx2[k], cx2);
        float ry = fminf(ry2[k], cy2);
        float wd = fmaxf(__fsub_rn(rx, lx), 0.0f);
        float ht = fmaxf(__fsub_rn(ry, ly), 0.0f);
        float inter = __fmul_rn(wd, ht);
        float den = __fadd_rn(__fsub_rn(__fadd_rn(rar[k], car), inter), 1e-7f);
        float iou = __fdiv_rn(inter, den);
        wreg[k] |= (iou > IOU_T ? 1u : 0u) << jj;
      }
    }
    if (cc == rg) {
      #pragma unroll
      for (int k = 0; k < 4; ++k)
        wreg[k] &= ~((2u << ((i0 + k) & 31)) - 1u);  // keep only j > i (strict)
    }
  }
  {
    uint4 out = make_uint4(wreg[0], wreg[1], wreg[2], wreg[3]);
    *(uint4*)&mask[((size_t)b * 32 + cc) * TOPK + i0] = out;
  }
  __syncthreads();   // drain mask stores
  if (tid == 0)
    __hip_atomic_fetch_add(&cntm[b], 1u, __ATOMIC_RELEASE, __HIP_MEMORY_SCOPE_AGENT);
  if (sblk != 0) return;

  // ---- phase 3 (sblk==0): early-gather, wait, stage, Jacobi, output ----
  const float4* rowv = (const float4*)(pred + ((size_t)b * NN + n) * NF);
  float4 r0 = rowv[0], r1 = rowv[1], r2 = rowv[2], r3 = rowv[3];

  if (tid == 0) {
    while (__hip_atomic_load(&cntm[b], __ATOMIC_RELAXED, __HIP_MEMORY_SCOPE_AGENT) < 8u)
      __builtin_amdgcn_s_sleep(16);
    (void)__hip_atomic_load(&cntm[b], __ATOMIC_ACQUIRE, __HIP_MEMORY_SCOPE_AGENT);
  }
  __syncthreads();

  // bulk stage: 128 KiB coalesced into pitch-257 LDS rows
  const uint4* gm4 = (const uint4*)(mask + (size_t)b * (32 * TOPK));
  #pragma unroll
  for (int q = 0; q < 8; ++q) {
    int idx4 = tid + q * 1024;          // uint4 index 0..8191
    int row = idx4 >> 8;                // 256 uint4 per mask word-row
    int col4 = idx4 & 255;
    sm4[row * PITCH + col4] = gm4[idx4];
  }
  __syncthreads();

  // Jacobi sweeps: K <- vb & ~S^T K until fixpoint (== exact greedy keep;
  // uniqueness by induction on smallest index, R10 derivation).
  {
    int l = tid & 31;                    // mask word this thread accumulates
    int chunk = tid >> 5;                // row block chunk*32..chunk*32+31
    const int rbase = l * PITCH + chunk * 8;
    uint32_t go = 1u;
    for (int sweep = 0; sweep < 1030 && go; ++sweep) {
      uint32_t kc = Kvec[chunk];         // kept bits for this row block
      uint32_t acc = 0;
      #pragma unroll
      for (int q = 0; q < 8; ++q) {
        uint4 v = sm4[rbase + q];
        acc |= (0u - ((kc >> (q * 4 + 0)) & 1u)) & v.x;
        acc |= (0u - ((kc >> (q * 4 + 1)) & 1u)) & v.y;
        acc |= (0u - ((kc >> (q * 4 + 2)) & 1u)) & v.z;
        acc |= (0u - ((kc >> (q * 4 + 3)) & 1u)) & v.w;
      }
      part[tid] = acc;
      __syncthreads();
      if (tid < 32) {
        uint32_t red = 0;
        #pragma unroll
        for (int c = 0; c < 32; ++c) red |= part[c * 32 + tid];
        uint32_t nk = vbs[tid] & ~red;
        uint64_t chg = __ballot(nk != Kvec[tid]);
        Kvec[tid] = nk;
        if (tid == 0) sflag = (chg != 0ull) ? 1u : 0u;
      }
      __syncthreads();
      go = sflag;
    }
  }

  // output: row already in registers (gathered before the spin)
  bool kept = (Kvec[tid >> 5] >> (tid & 31)) & 1u;
  float m = kept ? 1.0f : 0.0f;
  float score = __fmul_rn(r3.w, r1.x);   // == cls*obj, identical to reference path
  float hw = __fmul_rn(r0.z, 0.5f), hh = __fmul_rn(r0.w, 0.5f);
  float4 o0 = make_float4(__fsub_rn(r0.x, hw) * m, __fsub_rn(r0.y, hh) * m,
                          __fadd_rn(r0.x, hw) * m, __fadd_rn(r0.y, hh) * m);
  float4 o1 = make_float4(score * m, r1.y * m, r1.z * m, r1.w * m);
  float4 o2 = make_float4(r2.x * m, r2.y * m, r2.z * m, r2.w * m);
  float4 o3 = make_float4(r3.x * m, r3.y * m, r3.z * m, 0.0f);
  float4* dst = (float4*)(det + ((size_t)b * TOPK + tid) * NF);
  dst[0] = o0; dst[1] = o1; dst[2] = o2; dst[3] = o3;
  keep_out[(size_t)b * TOPK + tid] = m;
}

extern "C" void kernel_launch(void* const* d_in, const int* in_sizes, int n_in,
                              void* d_out, int out_size, void* d_ws, size_t ws_size,
                              hipStream_t stream) {
  const float* pred = (const float*)d_in[0];
  float* det = (float*)d_out;
  float* keep = det + (size_t)NB * TOPK * NF;

  uint8_t* ws = (uint8_t*)d_ws;
  size_t off = 0;
  uint32_t* keys = (uint32_t*)(ws + off); off += (size_t)NB * NN * 4;       // 3.2 MB
  uint32_t* mask = (uint32_t*)(ws + off); off += (size_t)NB * 32 * TOPK * 4;// 4 MB
  uint32_t* cnt = (uint32_t*)(ws + off);  off += (size_t)2 * NB * 4;        // 256 B

  hipMemsetAsync(cnt, 0, (size_t)2 * NB * 4, stream);
  dim3 g(NB, 8);
  k_nms<<<g, 1024, 0, stream>>>(pred, keys, mask, cnt, det, keep);
}

// Round 13
// 156.512 us; speedup vs baseline: 1.0379x; 1.0343x over previous
//
#include <hip/hip_runtime.h>
#include <stdint.h>

#define NB 32
#define NN 25200
#define NN4 6300          // NN/4, exact
#define RPS 3150          // rows per key-slab (NN/8, exact)
#define TOPK 1024
#define NF 16
#define CONF 0.25f
#define IOU_T 0.45f
#define NBIN 4096
#define CAP 2048
#define KEY_BASE 0xBE800001u  // lowest possible valid key (score just above 0.25)
#define PITCH 257             // uint4 row pitch in LDS (bank-spread, no swizzle)
#define CSTRIDE 32            // counter stride in uints = 128 B = one cache line

// monotone-ascending uint32 map of the reference's s = valid ? obj*cls : -1.0
// Valid entries (obj>CONF && score>CONF) map to keys >= KEY_BASE; all invalid
// entries (s=-1.0 -> 0x407FFFFF) land strictly below KEY_BASE.
__device__ __forceinline__ uint32_t score_key(float obj, float cls) {
  float score = __fmul_rn(cls, obj);
  bool valid = (obj > CONF) && (score > CONF);
  float s = valid ? score : -1.0f;
  uint32_t u = __float_as_uint(s);
  return (u & 0x80000000u) ? ~u : (u | 0x80000000u);
}

__device__ __forceinline__ uint64_t shfl_xor_u64(uint64_t v, int m) {
  uint32_t lo = __shfl_xor((uint32_t)v, m, 64);
  uint32_t hi = __shfl_xor((uint32_t)(v >> 32), m, 64);
  return ((uint64_t)hi << 32) | lo;
}

// R13 = R12 with ONE change: counters strided one cache line (128 B) apart.
// R12 post-mortem: the fused kernel's ~60us non-VALU stall is same-cache-line
// atomic serialization — all 32 cntk lived in ONE 128-B line, so each sync
// stage's 256 agent-scope fetch_add RMWs serialized at the coherence point
// (~0.1-0.2us each ≈ 25-50us/stage, two stages). This also retro-explains
// R10's unexplained k_maskscan residual (one 256-release stage, one line).
// Now: cntk[b] -> cnt[b*32], cntm[b] -> cnt[(NB+b)*32]; 8 releases per line.
// Everything else (phases, redundant select, balanced mask, Jacobi) is
// byte-identical to R12.
__global__ __launch_bounds__(1024, 4) void k_nms(const float* __restrict__ pred,
                                                 uint32_t* __restrict__ keys,
                                                 uint32_t* __restrict__ mask,
                                                 uint32_t* __restrict__ cnt,
                                                 float* __restrict__ det,
                                                 float* __restrict__ keep_out) {
  int b = blockIdx.x;
  int sblk = blockIdx.y;
  int tid = threadIdx.x;
  int lane = tid & 63, wid = tid >> 6;
  int rg = tid & 31;
  int cc = tid >> 5;

  __shared__ uint4 sm4[32 * PITCH];      // 131.6 KB big buffer (stage target)
  __shared__ uint32_t part[1024];
  __shared__ uint32_t Kvec[32];
  __shared__ uint32_t vbs[32];
  __shared__ uint32_t sflag;
  __shared__ uint32_t wsum[16];
  __shared__ uint32_t sh_bin;
  __shared__ uint32_t sh_cnt;

  // disjoint carves inside sm4 (all dead before the stage overwrites them):
  float* bx1 = (float*)sm4;              // 5 x 4 KB box arrays   [0, 20K)
  float* by1 = bx1 + TOPK;
  float* bx2 = by1 + TOPK;
  float* by2 = bx2 + TOPK;
  float* bar = by2 + TOPK;
  uint32_t* hist = (uint32_t*)(bar + TOPK);   // 16 KB              [20K, 36K)
  uint64_t* ent = (uint64_t*)(hist + NBIN);   // 16 KB              [36K, 52K)

  uint32_t* cntk = cnt + (size_t)b * CSTRIDE;             // one line per image
  uint32_t* cntm = cnt + (size_t)(NB + b) * CSTRIDE;      // one line per image

  // ---- phase 0: keys for this block's row chunk (full-grid HBM spread) ----
  {
    int base = sblk * RPS;
    #pragma unroll
    for (int q = 0; q < 4; ++q) {
      int t = tid + q * 1024;
      if (t < RPS) {
        int g = b * NN + base + t;
        const float* row = pred + (size_t)g * NF;
        keys[g] = score_key(row[4], row[15]);
      }
    }
  }
  __syncthreads();   // drain all threads' key stores
  if (tid == 0) {
    __hip_atomic_fetch_add(cntk, 1u, __ATOMIC_RELEASE, __HIP_MEMORY_SCOPE_AGENT);
    // every block waits for all 8 key slabs of its image, then one acquire
    while (__hip_atomic_load(cntk, __ATOMIC_RELAXED, __HIP_MEMORY_SCOPE_AGENT) < 8u)
      __builtin_amdgcn_s_sleep(16);
    (void)__hip_atomic_load(cntk, __ATOMIC_ACQUIRE, __HIP_MEMORY_SCOPE_AGENT);
  }
  __syncthreads();

  // ---- phase 1: select, run REDUNDANTLY by all 8 blocks of this image ----
  // Determinism: LDS-atomic histogram is order-invariant (sums); compaction
  // ticket order is erased by the bitonic total order on (key, ~n) with
  // unique n -> all 8 blocks derive IDENTICAL results.
  const uint4* kb4 = (const uint4*)(keys + (size_t)b * NN);
  #pragma unroll
  for (int k = 0; k < 4; ++k) hist[tid + 1024 * k] = 0;
  ent[tid] = 0; ent[tid + 1024] = 0;
  if (tid == 0) { sh_cnt = 0; sh_bin = 0; }
  __syncthreads();

  // load keys into registers (single global pass) + histogram
  uint4 kreg[7];
  #pragma unroll
  for (int k = 0; k < 7; ++k) {
    int i = tid + k * 1024;
    if (i < NN4) {
      kreg[k] = kb4[i];
      uint32_t kv[4] = {kreg[k].x, kreg[k].y, kreg[k].z, kreg[k].w};
      #pragma unroll
      for (int c = 0; c < 4; ++c) {
        uint32_t key = kv[c];
        if (key >= KEY_BASE) {
          uint32_t bin = (key - KEY_BASE) >> 12;
          if (bin > NBIN - 1) bin = NBIN - 1;
          atomicAdd(&hist[bin], 1u);
        }
      }
    }
  }
  __syncthreads();

  // descending-bin cumulative via shfl scan; find crossing bin
  uint32_t h[4]; uint32_t s = 0;
  #pragma unroll
  for (int k = 0; k < 4; ++k) { h[k] = hist[NBIN - 1 - (4 * tid + k)]; s += h[k]; }
  uint32_t my = s;
  #pragma unroll
  for (int d = 1; d < 64; d <<= 1) {
    uint32_t v = __shfl_up(s, d, 64);
    if (lane >= d) s += v;
  }
  if (lane == 63) wsum[wid] = s;
  __syncthreads();
  uint32_t base = 0;
  for (int w = 0; w < wid; ++w) base += wsum[w];
  uint32_t cum = base + s - my;  // exclusive prefix (descending bins)
  #pragma unroll
  for (int k = 0; k < 4; ++k) {
    if (cum < TOPK && cum + h[k] >= TOPK) sh_bin = (uint32_t)(NBIN - 1 - (4 * tid + k));
    cum += h[k];
  }
  __syncthreads();
  uint32_t thr = KEY_BASE + (sh_bin << 12);

  // compact from registers (no second global pass)
  #pragma unroll
  for (int k = 0; k < 7; ++k) {
    int i = tid + k * 1024;
    if (i < NN4) {
      uint32_t kv[4] = {kreg[k].x, kreg[k].y, kreg[k].z, kreg[k].w};
      #pragma unroll
      for (int c = 0; c < 4; ++c) {
        uint32_t key = kv[c];
        if (key >= thr) {
          uint32_t p = atomicAdd(&sh_cnt, 1u);
          if (p < CAP) ent[p] = ((uint64_t)key << 32) | (uint32_t)(~(uint32_t)(4 * i + c));
        }
      }
    }
  }
  __syncthreads();

  // register bitonic, 2048 descending, 2 elems/thread
  uint64_t v0 = ent[tid], v1 = ent[tid + 1024];
  for (unsigned kk = 2; kk <= CAP; kk <<= 1) {
    for (unsigned j = kk >> 1; j > 0; j >>= 1) {
      if (j == 1024) {
        uint64_t mx = v0 > v1 ? v0 : v1;
        uint64_t mn = v0 > v1 ? v1 : v0;
        v0 = mx; v1 = mn;  // desc=true for kk=2048
      } else if (j >= 64) {
        __syncthreads();
        ent[tid] = v0; ent[tid + 1024] = v1;
        __syncthreads();
        uint64_t p0 = ent[tid ^ j], p1 = ent[(tid ^ j) + 1024];
        bool low = ((tid & j) == 0);
        bool d0 = ((tid & kk) == 0);
        bool d1 = (((tid + 1024) & kk) == 0);
        v0 = (low != d0) ? (v0 < p0 ? v0 : p0) : (v0 > p0 ? v0 : p0);
        v1 = (low != d1) ? (v1 < p1 ? v1 : p1) : (v1 > p1 ? v1 : p1);
      } else {
        uint64_t p0 = shfl_xor_u64(v0, (int)j);
        uint64_t p1 = shfl_xor_u64(v1, (int)j);
        bool low = ((tid & j) == 0);
        bool d0 = ((tid & kk) == 0);
        bool d1 = (((tid + 1024) & kk) == 0);
        v0 = (low != d0) ? (v0 < p0 ? v0 : p0) : (v0 > p0 ? v0 : p0);
        v1 = (low != d1) ? (v1 < p1 ? v1 : p1) : (v1 > p1 ? v1 : p1);
      }
    }
  }
  uint32_t key = (uint32_t)(v0 >> 32);
  uint32_t nn = ~(uint32_t)(v0 & 0xFFFFFFFFu);
  if (nn >= NN) nn = 0;  // zero-pad path
  int n = (int)nn;       // this rank's source row — stays in a register

  // validity ballot straight into LDS (used by the tail block only)
  {
    bool valid = key >= KEY_BASE;
    uint64_t bal = __ballot(valid);
    if (lane == 0) {
      vbs[2 * wid] = (uint32_t)bal;  vbs[2 * wid + 1] = (uint32_t)(bal >> 32);
      Kvec[2 * wid] = (uint32_t)bal; Kvec[2 * wid + 1] = (uint32_t)(bal >> 32);
    }
  }

  // boxes: one scattered gather into LOCAL LDS (no global round-trip)
  {
    const float4* row = (const float4*)(pred + ((size_t)b * NN + n) * NF);
    float4 r0 = row[0];
    float hw = __fmul_rn(r0.z, 0.5f), hh = __fmul_rn(r0.w, 0.5f);
    float x1 = __fsub_rn(r0.x, hw), y1 = __fsub_rn(r0.y, hh);
    float x2 = __fadd_rn(r0.x, hw), y2 = __fadd_rn(r0.y, hh);
    bx1[tid] = x1; by1[tid] = y1; bx2[tid] = x2; by2[tid] = y2;
    bar[tid] = __fmul_rn(__fsub_rn(x2, x1), __fsub_rn(y2, y1));
  }
  __syncthreads();

  // ---- phase 2: mask, balanced quad-interleaved mapping ----
  // block sblk handles row-quads i0 = 32*rg + 4*sblk; iw == rg for every
  // block -> per-(rg) active words = 32-rg for ALL blocks -> equal work.
  int i0 = 32 * rg + 4 * sblk;    // rows i0..i0+3, all in word iw == rg
  uint32_t wreg[4] = {0u, 0u, 0u, 0u};
  if (cc >= rg) {
    float rx1[4], ry1[4], rx2[4], ry2[4], rar[4];
    #pragma unroll
    for (int k = 0; k < 4; ++k) {
      rx1[k] = bx1[i0 + k]; ry1[k] = by1[i0 + k];
      rx2[k] = bx2[i0 + k]; ry2[k] = by2[i0 + k]; rar[k] = bar[i0 + k];
    }
    for (int jj = 0; jj < 32; ++jj) {
      int j = cc * 32 + jj;
      float cx1 = bx1[j], cy1 = by1[j], cx2 = bx2[j], cy2 = by2[j], car = bar[j];
      #pragma unroll
      for (int k = 0; k < 4; ++k) {
        float lx = fmaxf(rx1[k], cx1);
        float ly = fmaxf(ry1[k], cy1);
        float rx = fminf(rx2[k], cx2);
        float ry = fminf(ry2[k], cy2);
        float wd = fmaxf(__fsub_rn(rx, lx), 0.0f);
        float ht = fmaxf(__fsub_rn(ry, ly), 0.0f);
        float inter = __fmul_rn(wd, ht);
        float den = __fadd_rn(__fsub_rn(__fadd_rn(rar[k], car), inter), 1e-7f);
        float iou = __fdiv_rn(inter, den);
        wreg[k] |= (iou > IOU_T ? 1u : 0u) << jj;
      }
    }
    if (cc == rg) {
      #pragma unroll
      for (int k = 0; k < 4; ++k)
        wreg[k] &= ~((2u << ((i0 + k) & 31)) - 1u);  // keep only j > i (strict)
    }
  }
  {
    uint4 out = make_uint4(wreg[0], wreg[1], wreg[2], wreg[3]);
    *(uint4*)&mask[((size_t)b * 32 + cc) * TOPK + i0] = out;
  }
  __syncthreads();   // drain mask stores
  if (tid == 0)
    __hip_atomic_fetch_add(cntm, 1u, __ATOMIC_RELEASE, __HIP_MEMORY_SCOPE_AGENT);
  if (sblk != 0) return;

  // ---- phase 3 (sblk==0): early-gather, wait, stage, Jacobi, output ----
  const float4* rowv = (const float4*)(pred + ((size_t)b * NN + n) * NF);
  float4 r0 = rowv[0], r1 = rowv[1], r2 = rowv[2], r3 = rowv[3];

  if (tid == 0) {
    while (__hip_atomic_load(cntm, __ATOMIC_RELAXED, __HIP_MEMORY_SCOPE_AGENT) < 8u)
      __builtin_amdgcn_s_sleep(16);
    (void)__hip_atomic_load(cntm, __ATOMIC_ACQUIRE, __HIP_MEMORY_SCOPE_AGENT);
  }
  __syncthreads();

  // bulk stage: 128 KiB coalesced into pitch-257 LDS rows
  const uint4* gm4 = (const uint4*)(mask + (size_t)b * (32 * TOPK));
  #pragma unroll
  for (int q = 0; q < 8; ++q) {
    int idx4 = tid + q * 1024;          // uint4 index 0..8191
    int row = idx4 >> 8;                // 256 uint4 per mask word-row
    int col4 = idx4 & 255;
    sm4[row * PITCH + col4] = gm4[idx4];
  }
  __syncthreads();

  // Jacobi sweeps: K <- vb & ~S^T K until fixpoint (== exact greedy keep;
  // uniqueness by induction on smallest index, R10 derivation).
  {
    int l = tid & 31;                    // mask word this thread accumulates
    int chunk = tid >> 5;                // row block chunk*32..chunk*32+31
    const int rbase = l * PITCH + chunk * 8;
    uint32_t go = 1u;
    for (int sweep = 0; sweep < 1030 && go; ++sweep) {
      uint32_t kc = Kvec[chunk];         // kept bits for this row block
      uint32_t acc = 0;
      #pragma unroll
      for (int q = 0; q < 8; ++q) {
        uint4 v = sm4[rbase + q];
        acc |= (0u - ((kc >> (q * 4 + 0)) & 1u)) & v.x;
        acc |= (0u - ((kc >> (q * 4 + 1)) & 1u)) & v.y;
        acc |= (0u - ((kc >> (q * 4 + 2)) & 1u)) & v.z;
        acc |= (0u - ((kc >> (q * 4 + 3)) & 1u)) & v.w;
      }
      part[tid] = acc;
      __syncthreads();
      if (tid < 32) {
        uint32_t red = 0;
        #pragma unroll
        for (int c = 0; c < 32; ++c) red |= part[c * 32 + tid];
        uint32_t nk = vbs[tid] & ~red;
        uint64_t chg = __ballot(nk != Kvec[tid]);
        Kvec[tid] = nk;
        if (tid == 0) sflag = (chg != 0ull) ? 1u : 0u;
      }
      __syncthreads();
      go = sflag;
    }
  }

  // output: row already in registers (gathered before the spin)
  bool kept = (Kvec[tid >> 5] >> (tid & 31)) & 1u;
  float m = kept ? 1.0f : 0.0f;
  float score = __fmul_rn(r3.w, r1.x);   // == cls*obj, identical to reference path
  float hw = __fmul_rn(r0.z, 0.5f), hh = __fmul_rn(r0.w, 0.5f);
  float4 o0 = make_float4(__fsub_rn(r0.x, hw) * m, __fsub_rn(r0.y, hh) * m,
                          __fadd_rn(r0.x, hw) * m, __fadd_rn(r0.y, hh) * m);
  float4 o1 = make_float4(score * m, r1.y * m, r1.z * m, r1.w * m);
  float4 o2 = make_float4(r2.x * m, r2.y * m, r2.z * m, r2.w * m);
  float4 o3 = make_float4(r3.x * m, r3.y * m, r3.z * m, 0.0f);
  float4* dst = (float4*)(det + ((size_t)b * TOPK + tid) * NF);
  dst[0] = o0; dst[1] = o1; dst[2] = o2; dst[3] = o3;
  keep_out[(size_t)b * TOPK + tid] = m;
}

extern "C" void kernel_launch(void* const* d_in, const int* in_sizes, int n_in,
                              void* d_out, int out_size, void* d_ws, size_t ws_size,
                              hipStream_t stream) {
  const float* pred = (const float*)d_in[0];
  float* det = (float*)d_out;
  float* keep = det + (size_t)NB * TOPK * NF;

  uint8_t* ws = (uint8_t*)d_ws;
  size_t off = 0;
  uint32_t* keys = (uint32_t*)(ws + off); off += (size_t)NB * NN * 4;       // 3.2 MB
  uint32_t* mask = (uint32_t*)(ws + off); off += (size_t)NB * 32 * TOPK * 4;// 4 MB
  uint32_t* cnt = (uint32_t*)(ws + off);  off += (size_t)2 * NB * CSTRIDE * 4; // 8 KB

  hipMemsetAsync(cnt, 0, (size_t)2 * NB * CSTRIDE * 4, stream);
  dim3 g(NB, 8);
  k_nms<<<g, 1024, 0, stream>>>(pred, keys, mask, cnt, det, keep);
}

// Round 14
// 146.493 us; speedup vs baseline: 1.1089x; 1.0684x over previous
//
#include <hip/hip_runtime.h>
#include <stdint.h>

#define NB 32
#define NN 25200
#define NN4 6300          // NN/4, exact
#define TOPK 1024
#define NF 16
#define CONF 0.25f
#define IOU_T 0.45f
#define NBIN 4096
#define CAP 2048
#define KEY_BASE 0xBE800001u  // lowest possible valid key (score just above 0.25)
#define PITCH 257             // uint4 row pitch in LDS (bank-spread, no swizzle)
#define CSTRIDE 32            // counter stride in uints = 128 B = one cache line

// monotone-ascending uint32 map of the reference's s = valid ? obj*cls : -1.0
// Valid entries (obj>CONF && score>CONF) map to keys >= KEY_BASE; all invalid
// entries (s=-1.0 -> 0x407FFFFF) land strictly below KEY_BASE.
__device__ __forceinline__ uint32_t score_key(float obj, float cls) {
  float score = __fmul_rn(cls, obj);
  bool valid = (obj > CONF) && (score > CONF);
  float s = valid ? score : -1.0f;
  uint32_t u = __float_as_uint(s);
  return (u & 0x80000000u) ? ~u : (u | 0x80000000u);
}

__device__ __forceinline__ uint64_t shfl_xor_u64(uint64_t v, int m) {
  uint32_t lo = __shfl_xor((uint32_t)v, m, 64);
  uint32_t hi = __shfl_xor((uint32_t)(v >> 32), m, 64);
  return ((uint64_t)hi << 32) | lo;
}

// Full-grid key compute (3150 blocks -> deep queue, BW-bound ~9us; the fused
// 1-block/CU variant was latency-starved — R11-R13 lesson). Also zeroes the
// strided slab counters.
__global__ void k_keys(const float* __restrict__ pred, uint32_t* __restrict__ keys,
                       uint32_t* __restrict__ cnt) {
  if (blockIdx.x == 0) {
    #pragma unroll
    for (int q = 0; q < 4; ++q) cnt[threadIdx.x + q * 256] = 0u;
  }
  int g = blockIdx.x * blockDim.x + threadIdx.x;
  if (g >= NB * NN) return;
  const float* row = pred + (size_t)g * NF;
  keys[g] = score_key(row[4], row[15]);
}

// One block per image (R10 body, unchanged): keys to registers, histogram ->
// crossing bin -> compact -> register bitonic 2048 descending. Exact
// jax.lax.top_k order. Epilogue materializes sel/boxes/areas/validity.
__global__ __launch_bounds__(1024) void k_select(const float* __restrict__ pred,
                                                 const uint32_t* __restrict__ keys,
                                                 int* __restrict__ sel,
                                                 float4* __restrict__ boxv,
                                                 float* __restrict__ arv,
                                                 uint32_t* __restrict__ vb) {
  int b = blockIdx.x;
  int tid = threadIdx.x;
  int lane = tid & 63, wid = tid >> 6;
  const uint4* kb4 = (const uint4*)(keys + (size_t)b * NN);
  __shared__ uint32_t hist[NBIN];
  __shared__ uint64_t ent[CAP];
  __shared__ uint32_t wsum[16];
  __shared__ uint32_t sh_bin;
  __shared__ uint32_t sh_cnt;
  #pragma unroll
  for (int k = 0; k < 4; ++k) hist[tid + 1024 * k] = 0;
  ent[tid] = 0; ent[tid + 1024] = 0;
  if (tid == 0) { sh_cnt = 0; sh_bin = 0; }
  __syncthreads();

  uint4 kreg[7];
  #pragma unroll
  for (int k = 0; k < 7; ++k) {
    int i = tid + k * 1024;
    if (i < NN4) {
      kreg[k] = kb4[i];
      uint32_t kv[4] = {kreg[k].x, kreg[k].y, kreg[k].z, kreg[k].w};
      #pragma unroll
      for (int c = 0; c < 4; ++c) {
        uint32_t key = kv[c];
        if (key >= KEY_BASE) {
          uint32_t bin = (key - KEY_BASE) >> 12;
          if (bin > NBIN - 1) bin = NBIN - 1;
          atomicAdd(&hist[bin], 1u);
        }
      }
    }
  }
  __syncthreads();

  uint32_t h[4]; uint32_t s = 0;
  #pragma unroll
  for (int k = 0; k < 4; ++k) { h[k] = hist[NBIN - 1 - (4 * tid + k)]; s += h[k]; }
  uint32_t my = s;
  #pragma unroll
  for (int d = 1; d < 64; d <<= 1) {
    uint32_t v = __shfl_up(s, d, 64);
    if (lane >= d) s += v;
  }
  if (lane == 63) wsum[wid] = s;
  __syncthreads();
  uint32_t base = 0;
  for (int w = 0; w < wid; ++w) base += wsum[w];
  uint32_t cum = base + s - my;  // exclusive prefix (descending bins)
  #pragma unroll
  for (int k = 0; k < 4; ++k) {
    if (cum < TOPK && cum + h[k] >= TOPK) sh_bin = (uint32_t)(NBIN - 1 - (4 * tid + k));
    cum += h[k];
  }
  __syncthreads();
  uint32_t thr = KEY_BASE + (sh_bin << 12);

  #pragma unroll
  for (int k = 0; k < 7; ++k) {
    int i = tid + k * 1024;
    if (i < NN4) {
      uint32_t kv[4] = {kreg[k].x, kreg[k].y, kreg[k].z, kreg[k].w};
      #pragma unroll
      for (int c = 0; c < 4; ++c) {
        uint32_t key = kv[c];
        if (key >= thr) {
          uint32_t p = atomicAdd(&sh_cnt, 1u);
          if (p < CAP) ent[p] = ((uint64_t)key << 32) | (uint32_t)(~(uint32_t)(4 * i + c));
        }
      }
    }
  }
  __syncthreads();

  uint64_t v0 = ent[tid], v1 = ent[tid + 1024];
  for (unsigned kk = 2; kk <= CAP; kk <<= 1) {
    for (unsigned j = kk >> 1; j > 0; j >>= 1) {
      if (j == 1024) {
        uint64_t mx = v0 > v1 ? v0 : v1;
        uint64_t mn = v0 > v1 ? v1 : v0;
        v0 = mx; v1 = mn;  // desc=true for kk=2048
      } else if (j >= 64) {
        __syncthreads();
        ent[tid] = v0; ent[tid + 1024] = v1;
        __syncthreads();
        uint64_t p0 = ent[tid ^ j], p1 = ent[(tid ^ j) + 1024];
        bool low = ((tid & j) == 0);
        bool d0 = ((tid & kk) == 0);
        bool d1 = (((tid + 1024) & kk) == 0);
        v0 = (low != d0) ? (v0 < p0 ? v0 : p0) : (v0 > p0 ? v0 : p0);
        v1 = (low != d1) ? (v1 < p1 ? v1 : p1) : (v1 > p1 ? v1 : p1);
      } else {
        uint64_t p0 = shfl_xor_u64(v0, (int)j);
        uint64_t p1 = shfl_xor_u64(v1, (int)j);
        bool low = ((tid & j) == 0);
        bool d0 = ((tid & kk) == 0);
        bool d1 = (((tid + 1024) & kk) == 0);
        v0 = (low != d0) ? (v0 < p0 ? v0 : p0) : (v0 > p0 ? v0 : p0);
        v1 = (low != d1) ? (v1 < p1 ? v1 : p1) : (v1 > p1 ? v1 : p1);
      }
    }
  }
  uint32_t key = (uint32_t)(v0 >> 32);
  uint32_t n = ~(uint32_t)(v0 & 0xFFFFFFFFu);
  if (n >= NN) n = 0;  // zero-pad path
  sel[(size_t)b * TOPK + tid] = (int)n;

  bool valid = key >= KEY_BASE;
  uint64_t bal = __ballot(valid);
  if (lane == 0) {
    vb[(size_t)b * 32 + 2 * wid] = (uint32_t)bal;
    vb[(size_t)b * 32 + 2 * wid + 1] = (uint32_t)(bal >> 32);
  }

  {
    const float4* row = (const float4*)(pred + ((size_t)b * NN + n) * NF);
    float4 r0 = row[0];
    float hw = __fmul_rn(r0.z, 0.5f), hh = __fmul_rn(r0.w, 0.5f);
    float x1 = __fsub_rn(r0.x, hw), y1 = __fsub_rn(r0.y, hh);
    float x2 = __fadd_rn(r0.x, hw), y2 = __fadd_rn(r0.y, hh);
    boxv[(size_t)b * TOPK + tid] = make_float4(x1, y1, x2, y2);
    arv[(size_t)b * TOPK + tid] = __fmul_rn(__fsub_rn(x2, x1), __fsub_rn(y2, y1));
  }
}

// R14: R10's fused mask+Jacobi+output with two measured-mechanism fixes:
//  (a) PAIR-BALANCED COALESCED mask mapping: block s computes the FIRST 16
//      row-quads of region s and the LAST 16 of region 7-s. Active-word sum
//      per block = (504-64s) + (472-64(7-s)) = 528 for EVERY s — exactly
//      balanced — and each 16-lane group stores a contiguous 256-B segment
//      (R11's quad-interleave was balanced but scattered stores at 128-B
//      stride: WRITE_SIZE 6.3->10.3 MB; this keeps 6.3).
//  (b) STRIDED counters (one 128-B line per image; R13 measured -13us from
//      de-serializing the release storm on shared lines).
// Everything else byte-identical to R10.
__global__ __launch_bounds__(1024, 4) void k_maskscan(const float* __restrict__ pred,
                                                      const int* __restrict__ sel,
                                                      const float4* __restrict__ boxv,
                                                      const float* __restrict__ arv,
                                                      const uint32_t* __restrict__ vb,
                                                      uint32_t* __restrict__ mask,
                                                      uint32_t* __restrict__ cnt,
                                                      float* __restrict__ det,
                                                      float* __restrict__ keep_out) {
  int b = blockIdx.x;
  int sblk = blockIdx.y;
  int tid = threadIdx.x;
  int rg = tid & 31;
  int cc = tid >> 5;
  __shared__ uint4 sm4[32 * PITCH];      // 131.6 KB staged mask, pitch-257
  __shared__ uint32_t part[1024];
  __shared__ uint32_t Kvec[32];
  __shared__ uint32_t vbs[32];
  __shared__ uint32_t sflag;
  // phase-A overlay: box arrays live in the first 20 KB of sm4
  float* bx1 = (float*)sm4;
  float* by1 = bx1 + TOPK;
  float* bx2 = by1 + TOPK;
  float* by2 = bx2 + TOPK;
  float* bar = by2 + TOPK;

  uint32_t* cntm = cnt + (size_t)b * CSTRIDE;   // one cache line per image

  // ---- phase A: mask, pair-balanced coalesced mapping ----
  {
    float4 bb = boxv[(size_t)b * TOPK + tid];
    bx1[tid] = bb.x; by1[tid] = bb.y; bx2[tid] = bb.z; by2[tid] = bb.w;
    bar[tid] = arv[(size_t)b * TOPK + tid];
  }
  __syncthreads();
  // quad index: rg<16 -> q = 32*sblk + rg ; rg>=16 -> q = 32*(7-sblk) + rg
  int q = (rg < 16) ? (32 * sblk + rg) : (32 * (7 - sblk) + rg);
  int i0 = 4 * q;                 // rows i0..i0+3, all in word iw
  int iw = q >> 3;
  uint32_t wreg[4] = {0u, 0u, 0u, 0u};
  if (cc >= iw) {
    float rx1[4], ry1[4], rx2[4], ry2[4], rar[4];
    #pragma unroll
    for (int k = 0; k < 4; ++k) {
      rx1[k] = bx1[i0 + k]; ry1[k] = by1[i0 + k];
      rx2[k] = bx2[i0 + k]; ry2[k] = by2[i0 + k]; rar[k] = bar[i0 + k];
    }
    for (int jj = 0; jj < 32; ++jj) {
      int j = cc * 32 + jj;
      float cx1 = bx1[j], cy1 = by1[j], cx2 = bx2[j], cy2 = by2[j], car = bar[j];
      #pragma unroll
      for (int k = 0; k < 4; ++k) {
        float lx = fmaxf(rx1[k], cx1);
        float ly = fmaxf(ry1[k], cy1);
        float rx = fminf(rx2[k], cx2);
        float ry = fminf(ry2[k], cy2);
        float wd = fmaxf(__fsub_rn(rx, lx), 0.0f);
        float ht = fmaxf(__fsub_rn(ry, ly), 0.0f);
        float inter = __fmul_rn(wd, ht);
        float den = __fadd_rn(__fsub_rn(__fadd_rn(rar[k], car), inter), 1e-7f);
        float iou = __fdiv_rn(inter, den);
        wreg[k] |= (iou > IOU_T ? 1u : 0u) << jj;
      }
    }
    if (cc == iw) {
      #pragma unroll
      for (int k = 0; k < 4; ++k)
        wreg[k] &= ~((2u << ((i0 + k) & 31)) - 1u);  // keep only j > i (strict)
    }
  }
  {
    uint4 out = make_uint4(wreg[0], wreg[1], wreg[2], wreg[3]);
    *(uint4*)&mask[((size_t)b * 32 + cc) * TOPK + i0] = out;
  }

  // publish this slab: barrier drains every thread's vmcnt, then ONE
  // release-add (own cache line) bumps the counter.
  __syncthreads();
  if (tid == 0)
    __hip_atomic_fetch_add(cntm, 1u, __ATOMIC_RELEASE, __HIP_MEMORY_SCOPE_AGENT);
  if (sblk != 0) return;

  // ---- phase B (sblk==0 only): early-gather, wait, stage, Jacobi, output ----
  uint32_t kw0 = 0;
  if (tid < 32) kw0 = vb[(size_t)b * 32 + tid];
  int n = sel[(size_t)b * TOPK + tid];
  const float4* rowv = (const float4*)(pred + ((size_t)b * NN + n) * NF);
  float4 r0 = rowv[0], r1 = rowv[1], r2 = rowv[2], r3 = rowv[3];

  if (tid == 0) {
    while (__hip_atomic_load(cntm, __ATOMIC_RELAXED, __HIP_MEMORY_SCOPE_AGENT) < 8u)
      __builtin_amdgcn_s_sleep(16);
    (void)__hip_atomic_load(cntm, __ATOMIC_ACQUIRE, __HIP_MEMORY_SCOPE_AGENT);
  }
  __syncthreads();

  // bulk stage: 128 KiB coalesced into pitch-257 LDS rows
  const uint4* gm4 = (const uint4*)(mask + (size_t)b * (32 * TOPK));
  #pragma unroll
  for (int qq = 0; qq < 8; ++qq) {
    int idx4 = tid + qq * 1024;         // uint4 index 0..8191
    int row = idx4 >> 8;                // 256 uint4 per mask word-row
    int col4 = idx4 & 255;
    sm4[row * PITCH + col4] = gm4[idx4];
  }
  if (tid < 32) { vbs[tid] = kw0; Kvec[tid] = kw0; }
  __syncthreads();

  // Jacobi sweeps: K <- vb & ~S^T K until fixpoint (== exact greedy keep;
  // uniqueness by induction on smallest index — R10 derivation).
  {
    int l = tid & 31;                    // mask word this thread accumulates
    int chunk = tid >> 5;                // row block chunk*32..chunk*32+31
    const int rbase = l * PITCH + chunk * 8;
    uint32_t go = 1u;
    for (int sweep = 0; sweep < 1030 && go; ++sweep) {
      uint32_t kc = Kvec[chunk];         // kept bits for this row block
      uint32_t acc = 0;
      #pragma unroll
      for (int qq = 0; qq < 8; ++qq) {
        uint4 v = sm4[rbase + qq];
        acc |= (0u - ((kc >> (qq * 4 + 0)) & 1u)) & v.x;
        acc |= (0u - ((kc >> (qq * 4 + 1)) & 1u)) & v.y;
        acc |= (0u - ((kc >> (qq * 4 + 2)) & 1u)) & v.z;
        acc |= (0u - ((kc >> (qq * 4 + 3)) & 1u)) & v.w;
      }
      part[tid] = acc;
      __syncthreads();
      if (tid < 32) {
        uint32_t red = 0;
        #pragma unroll
        for (int c = 0; c < 32; ++c) red |= part[c * 32 + tid];
        uint32_t nk = vbs[tid] & ~red;
        uint64_t chg = __ballot(nk != Kvec[tid]);
        Kvec[tid] = nk;
        if (tid == 0) sflag = (chg != 0ull) ? 1u : 0u;
      }
      __syncthreads();
      go = sflag;
    }
  }

  // output: row already in registers (gathered before the spin)
  bool kept = (Kvec[tid >> 5] >> (tid & 31)) & 1u;
  float m = kept ? 1.0f : 0.0f;
  float score = __fmul_rn(r3.w, r1.x);   // == cls*obj, identical to reference path
  float hw = __fmul_rn(r0.z, 0.5f), hh = __fmul_rn(r0.w, 0.5f);
  float4 o0 = make_float4(__fsub_rn(r0.x, hw) * m, __fsub_rn(r0.y, hh) * m,
                          __fadd_rn(r0.x, hw) * m, __fadd_rn(r0.y, hh) * m);
  float4 o1 = make_float4(score * m, r1.y * m, r1.z * m, r1.w * m);
  float4 o2 = make_float4(r2.x * m, r2.y * m, r2.z * m, r2.w * m);
  float4 o3 = make_float4(r3.x * m, r3.y * m, r3.z * m, 0.0f);
  float4* dst = (float4*)(det + ((size_t)b * TOPK + tid) * NF);
  dst[0] = o0; dst[1] = o1; dst[2] = o2; dst[3] = o3;
  keep_out[(size_t)b * TOPK + tid] = m;
}

extern "C" void kernel_launch(void* const* d_in, const int* in_sizes, int n_in,
                              void* d_out, int out_size, void* d_ws, size_t ws_size,
                              hipStream_t stream) {
  const float* pred = (const float*)d_in[0];
  float* det = (float*)d_out;
  float* keep = det + (size_t)NB * TOPK * NF;

  uint8_t* ws = (uint8_t*)d_ws;
  size_t off = 0;
  uint32_t* keys = (uint32_t*)(ws + off); off += (size_t)NB * NN * 4;       // 3.2 MB
  int* sel = (int*)(ws + off);            off += (size_t)NB * TOPK * 4;     // 128 KB
  uint32_t* mask = (uint32_t*)(ws + off); off += (size_t)NB * 32 * TOPK * 4;// 4 MB
  float4* boxv = (float4*)(ws + off);     off += (size_t)NB * TOPK * 16;    // 512 KB
  float* arv = (float*)(ws + off);        off += (size_t)NB * TOPK * 4;     // 128 KB
  uint32_t* vb = (uint32_t*)(ws + off);   off += (size_t)NB * 32 * 4;       // 4 KB
  uint32_t* cnt = (uint32_t*)(ws + off);  off += (size_t)NB * CSTRIDE * 4;  // 4 KB

  k_keys<<<(NB * NN + 255) / 256, 256, 0, stream>>>(pred, keys, cnt);
  k_select<<<NB, 1024, 0, stream>>>(pred, keys, sel, boxv, arv, vb);
  dim3 gm(NB, 8);
  k_maskscan<<<gm, 1024, 0, stream>>>(pred, sel, boxv, arv, vb, mask, cnt, det, keep);
}

// Round 15
// 142.851 us; speedup vs baseline: 1.1372x; 1.0255x over previous
//
#include <hip/hip_runtime.h>
#include <stdint.h>

#define NB 32
#define NN 25200
#define NN4 6300          // NN/4, exact
#define TOPK 1024
#define NF 16
#define CONF 0.25f
#define IOU_T 0.45f
#define NBIN 4096
#define CAP 2048
#define KEY_BASE 0xBE800001u  // lowest possible valid key (score just above 0.25)
#define PITCH 257             // uint4 row pitch in LDS (bank-spread, no swizzle)
#define CSTRIDE 32            // counter stride in uints = 128 B = one cache line

// monotone-ascending uint32 map of the reference's s = valid ? obj*cls : -1.0
// Valid entries (obj>CONF && score>CONF) map to keys >= KEY_BASE; all invalid
// entries (s=-1.0 -> 0x407FFFFF) land strictly below KEY_BASE.
__device__ __forceinline__ uint32_t score_key(float obj, float cls) {
  float score = __fmul_rn(cls, obj);
  bool valid = (obj > CONF) && (score > CONF);
  float s = valid ? score : -1.0f;
  uint32_t u = __float_as_uint(s);
  return (u & 0x80000000u) ? ~u : (u | 0x80000000u);
}

__device__ __forceinline__ uint64_t shfl_xor_u64(uint64_t v, int m) {
  uint32_t lo = __shfl_xor((uint32_t)v, m, 64);
  uint32_t hi = __shfl_xor((uint32_t)(v >> 32), m, 64);
  return ((uint64_t)hi << 32) | lo;
}

// Full-grid key compute — kept standalone ON PURPOSE (R15 structure-matrix
// resolution): 3150 blocks give a deep queue and ~9us BW-bound execution;
// folding keys into the 256-block fused kernel latency-starved it (R11-R13,
// ~+15us). Also zeroes the strided slab counters for k_nms.
__global__ void k_keys(const float* __restrict__ pred, uint32_t* __restrict__ keys,
                       uint32_t* __restrict__ cnt) {
  if (blockIdx.x == 0) {
    #pragma unroll
    for (int q = 0; q < 4; ++q) cnt[threadIdx.x + q * 256] = 0u;
  }
  int g = blockIdx.x * blockDim.x + threadIdx.x;
  if (g >= NB * NN) return;
  const float* row = pred + (size_t)g * NF;
  keys[g] = score_key(row[4], row[15]);
}

// R15: TWO-launch hybrid — the one untested cell of the structure matrix.
// R13/R14 priced a launch boundary at ~16us; R12 proved redundant select is
// exact; R13 proved strided counters de-serialize the release storm; R14's
// pair-balanced mapping keeps mask work equal AND stores coalesced. This
// kernel combines every phase in its measured-best form with ONE sync storm:
//   1. select: ALL 256 blocks run the histogram+compact+bitonic select
//      REDUNDANTLY from global keys (kernel boundary orders the key writes —
//      no keys-sync needed). Determinism: the LDS-atomic histogram is
//      order-invariant (sums); compaction ticket order is erased by the
//      bitonic total order on (key, ~n), n unique -> all 8 blocks of an
//      image derive IDENTICAL n/boxes/ballot (absmax 0 in R12/R13).
//   2. mask: pair-balanced coalesced mapping — block s does the first 16
//      row-quads of region s + last 16 of region 7-s (528 active words for
//      every block, 256-B contiguous store segments).
//   3. one release (own 128-B line) per block; workers exit.
//   4. tail (sblk==0): early output-gather, relaxed-poll spin + single
//      acquire, 128-KiB pitch-257 LDS stage, Jacobi fixpoint (== exact
//      greedy, R10 derivation), write det/keep.
__global__ __launch_bounds__(1024, 4) void k_nms(const float* __restrict__ pred,
                                                 const uint32_t* __restrict__ keys,
                                                 uint32_t* __restrict__ mask,
                                                 uint32_t* __restrict__ cnt,
                                                 float* __restrict__ det,
                                                 float* __restrict__ keep_out) {
  int b = blockIdx.x;
  int sblk = blockIdx.y;
  int tid = threadIdx.x;
  int lane = tid & 63, wid = tid >> 6;
  int rg = tid & 31;
  int cc = tid >> 5;

  __shared__ uint4 sm4[32 * PITCH];      // 131.6 KB big buffer (stage target)
  __shared__ uint32_t part[1024];
  __shared__ uint32_t Kvec[32];
  __shared__ uint32_t vbs[32];
  __shared__ uint32_t sflag;
  __shared__ uint32_t wsum[16];
  __shared__ uint32_t sh_bin;
  __shared__ uint32_t sh_cnt;

  // disjoint carves inside sm4 (all dead before the stage overwrites them):
  float* bx1 = (float*)sm4;              // 5 x 4 KB box arrays   [0, 20K)
  float* by1 = bx1 + TOPK;
  float* bx2 = by1 + TOPK;
  float* by2 = bx2 + TOPK;
  float* bar = by2 + TOPK;
  uint32_t* hist = (uint32_t*)(bar + TOPK);   // 16 KB              [20K, 36K)
  uint64_t* ent = (uint64_t*)(hist + NBIN);   // 16 KB              [36K, 52K)

  uint32_t* cntm = cnt + (size_t)b * CSTRIDE;   // one cache line per image

  // ---- phase 1: select, run REDUNDANTLY by all 8 blocks of this image ----
  const uint4* kb4 = (const uint4*)(keys + (size_t)b * NN);
  #pragma unroll
  for (int k = 0; k < 4; ++k) hist[tid + 1024 * k] = 0;
  ent[tid] = 0; ent[tid + 1024] = 0;
  if (tid == 0) { sh_cnt = 0; sh_bin = 0; }
  __syncthreads();

  // load keys into registers (single global pass) + histogram
  uint4 kreg[7];
  #pragma unroll
  for (int k = 0; k < 7; ++k) {
    int i = tid + k * 1024;
    if (i < NN4) {
      kreg[k] = kb4[i];
      uint32_t kv[4] = {kreg[k].x, kreg[k].y, kreg[k].z, kreg[k].w};
      #pragma unroll
      for (int c = 0; c < 4; ++c) {
        uint32_t key = kv[c];
        if (key >= KEY_BASE) {
          uint32_t bin = (key - KEY_BASE) >> 12;
          if (bin > NBIN - 1) bin = NBIN - 1;
          atomicAdd(&hist[bin], 1u);
        }
      }
    }
  }
  __syncthreads();

  // descending-bin cumulative via shfl scan; find crossing bin
  uint32_t h[4]; uint32_t s = 0;
  #pragma unroll
  for (int k = 0; k < 4; ++k) { h[k] = hist[NBIN - 1 - (4 * tid + k)]; s += h[k]; }
  uint32_t my = s;
  #pragma unroll
  for (int d = 1; d < 64; d <<= 1) {
    uint32_t v = __shfl_up(s, d, 64);
    if (lane >= d) s += v;
  }
  if (lane == 63) wsum[wid] = s;
  __syncthreads();
  uint32_t base = 0;
  for (int w = 0; w < wid; ++w) base += wsum[w];
  uint32_t cum = base + s - my;  // exclusive prefix (descending bins)
  #pragma unroll
  for (int k = 0; k < 4; ++k) {
    if (cum < TOPK && cum + h[k] >= TOPK) sh_bin = (uint32_t)(NBIN - 1 - (4 * tid + k));
    cum += h[k];
  }
  __syncthreads();
  uint32_t thr = KEY_BASE + (sh_bin << 12);

  // compact from registers (no second global pass)
  #pragma unroll
  for (int k = 0; k < 7; ++k) {
    int i = tid + k * 1024;
    if (i < NN4) {
      uint32_t kv[4] = {kreg[k].x, kreg[k].y, kreg[k].z, kreg[k].w};
      #pragma unroll
      for (int c = 0; c < 4; ++c) {
        uint32_t key = kv[c];
        if (key >= thr) {
          uint32_t p = atomicAdd(&sh_cnt, 1u);
          if (p < CAP) ent[p] = ((uint64_t)key << 32) | (uint32_t)(~(uint32_t)(4 * i + c));
        }
      }
    }
  }
  __syncthreads();

  // register bitonic, 2048 descending, 2 elems/thread (canonicalizes any
  // compaction arrival order -> identical results across the 8 blocks)
  uint64_t v0 = ent[tid], v1 = ent[tid + 1024];
  for (unsigned kk = 2; kk <= CAP; kk <<= 1) {
    for (unsigned j = kk >> 1; j > 0; j >>= 1) {
      if (j == 1024) {
        uint64_t mx = v0 > v1 ? v0 : v1;
        uint64_t mn = v0 > v1 ? v1 : v0;
        v0 = mx; v1 = mn;  // desc=true for kk=2048
      } else if (j >= 64) {
        __syncthreads();
        ent[tid] = v0; ent[tid + 1024] = v1;
        __syncthreads();
        uint64_t p0 = ent[tid ^ j], p1 = ent[(tid ^ j) + 1024];
        bool low = ((tid & j) == 0);
        bool d0 = ((tid & kk) == 0);
        bool d1 = (((tid + 1024) & kk) == 0);
        v0 = (low != d0) ? (v0 < p0 ? v0 : p0) : (v0 > p0 ? v0 : p0);
        v1 = (low != d1) ? (v1 < p1 ? v1 : p1) : (v1 > p1 ? v1 : p1);
      } else {
        uint64_t p0 = shfl_xor_u64(v0, (int)j);
        uint64_t p1 = shfl_xor_u64(v1, (int)j);
        bool low = ((tid & j) == 0);
        bool d0 = ((tid & kk) == 0);
        bool d1 = (((tid + 1024) & kk) == 0);
        v0 = (low != d0) ? (v0 < p0 ? v0 : p0) : (v0 > p0 ? v0 : p0);
        v1 = (low != d1) ? (v1 < p1 ? v1 : p1) : (v1 > p1 ? v1 : p1);
      }
    }
  }
  uint32_t key = (uint32_t)(v0 >> 32);
  uint32_t nn = ~(uint32_t)(v0 & 0xFFFFFFFFu);
  if (nn >= NN) nn = 0;  // zero-pad path
  int n = (int)nn;       // this rank's source row — stays in a register

  // validity ballot straight into LDS (used by the tail block only)
  {
    bool valid = key >= KEY_BASE;
    uint64_t bal = __ballot(valid);
    if (lane == 0) {
      vbs[2 * wid] = (uint32_t)bal;  vbs[2 * wid + 1] = (uint32_t)(bal >> 32);
      Kvec[2 * wid] = (uint32_t)bal; Kvec[2 * wid + 1] = (uint32_t)(bal >> 32);
    }
  }

  // boxes: one scattered gather into LOCAL LDS (no global round-trip)
  {
    const float4* row = (const float4*)(pred + ((size_t)b * NN + n) * NF);
    float4 r0 = row[0];
    float hw = __fmul_rn(r0.z, 0.5f), hh = __fmul_rn(r0.w, 0.5f);
    float x1 = __fsub_rn(r0.x, hw), y1 = __fsub_rn(r0.y, hh);
    float x2 = __fadd_rn(r0.x, hw), y2 = __fadd_rn(r0.y, hh);
    bx1[tid] = x1; by1[tid] = y1; bx2[tid] = x2; by2[tid] = y2;
    bar[tid] = __fmul_rn(__fsub_rn(x2, x1), __fsub_rn(y2, y1));
  }
  __syncthreads();

  // ---- phase 2: mask, pair-balanced coalesced mapping (R14) ----
  // quad index: rg<16 -> q = 32*sblk + rg ; rg>=16 -> q = 32*(7-sblk) + rg.
  // Active-word sum per block = 528 for every s (exact balance), and each
  // 16-lane group stores a contiguous 256-B segment (coalesced).
  int q = (rg < 16) ? (32 * sblk + rg) : (32 * (7 - sblk) + rg);
  int i0 = 4 * q;                 // rows i0..i0+3, all in word iw
  int iw = q >> 3;
  uint32_t wreg[4] = {0u, 0u, 0u, 0u};
  if (cc >= iw) {
    float rx1[4], ry1[4], rx2[4], ry2[4], rar[4];
    #pragma unroll
    for (int k = 0; k < 4; ++k) {
      rx1[k] = bx1[i0 + k]; ry1[k] = by1[i0 + k];
      rx2[k] = bx2[i0 + k]; ry2[k] = by2[i0 + k]; rar[k] = bar[i0 + k];
    }
    for (int jj = 0; jj < 32; ++jj) {
      int j = cc * 32 + jj;
      float cx1 = bx1[j], cy1 = by1[j], cx2 = bx2[j], cy2 = by2[j], car = bar[j];
      #pragma unroll
      for (int k = 0; k < 4; ++k) {
        float lx = fmaxf(rx1[k], cx1);
        float ly = fmaxf(ry1[k], cy1);
        float rx = fminf(rx2[k], cx2);
        float ry = fminf(ry2[k], cy2);
        float wd = fmaxf(__fsub_rn(rx, lx), 0.0f);
        float ht = fmaxf(__fsub_rn(ry, ly), 0.0f);
        float inter = __fmul_rn(wd, ht);
        float den = __fadd_rn(__fsub_rn(__fadd_rn(rar[k], car), inter), 1e-7f);
        float iou = __fdiv_rn(inter, den);
        wreg[k] |= (iou > IOU_T ? 1u : 0u) << jj;
      }
    }
    if (cc == iw) {
      #pragma unroll
      for (int k = 0; k < 4; ++k)
        wreg[k] &= ~((2u << ((i0 + k) & 31)) - 1u);  // keep only j > i (strict)
    }
  }
  {
    uint4 out = make_uint4(wreg[0], wreg[1], wreg[2], wreg[3]);
    *(uint4*)&mask[((size_t)b * 32 + cc) * TOPK + i0] = out;
  }
  __syncthreads();   // drain mask stores
  if (tid == 0)
    __hip_atomic_fetch_add(cntm, 1u, __ATOMIC_RELEASE, __HIP_MEMORY_SCOPE_AGENT);
  if (sblk != 0) return;

  // ---- phase 3 (sblk==0): early-gather, wait, stage, Jacobi, output ----
  const float4* rowv = (const float4*)(pred + ((size_t)b * NN + n) * NF);
  float4 r0 = rowv[0], r1 = rowv[1], r2 = rowv[2], r3 = rowv[3];

  if (tid == 0) {
    while (__hip_atomic_load(cntm, __ATOMIC_RELAXED, __HIP_MEMORY_SCOPE_AGENT) < 8u)
      __builtin_amdgcn_s_sleep(16);
    (void)__hip_atomic_load(cntm, __ATOMIC_ACQUIRE, __HIP_MEMORY_SCOPE_AGENT);
  }
  __syncthreads();

  // bulk stage: 128 KiB coalesced into pitch-257 LDS rows
  const uint4* gm4 = (const uint4*)(mask + (size_t)b * (32 * TOPK));
  #pragma unroll
  for (int qq = 0; qq < 8; ++qq) {
    int idx4 = tid + qq * 1024;         // uint4 index 0..8191
    int row = idx4 >> 8;                // 256 uint4 per mask word-row
    int col4 = idx4 & 255;
    sm4[row * PITCH + col4] = gm4[idx4];
  }
  __syncthreads();

  // Jacobi sweeps: K <- vb & ~S^T K until fixpoint (== exact greedy keep;
  // uniqueness by induction on smallest index — R10 derivation).
  {
    int l = tid & 31;                    // mask word this thread accumulates
    int chunk = tid >> 5;                // row block chunk*32..chunk*32+31
    const int rbase = l * PITCH + chunk * 8;
    uint32_t go = 1u;
    for (int sweep = 0; sweep < 1030 && go; ++sweep) {
      uint32_t kc = Kvec[chunk];         // kept bits for this row block
      uint32_t acc = 0;
      #pragma unroll
      for (int qq = 0; qq < 8; ++qq) {
        uint4 v = sm4[rbase + qq];
        acc |= (0u - ((kc >> (qq * 4 + 0)) & 1u)) & v.x;
        acc |= (0u - ((kc >> (qq * 4 + 1)) & 1u)) & v.y;
        acc |= (0u - ((kc >> (qq * 4 + 2)) & 1u)) & v.z;
        acc |= (0u - ((kc >> (qq * 4 + 3)) & 1u)) & v.w;
      }
      part[tid] = acc;
      __syncthreads();
      if (tid < 32) {
        uint32_t red = 0;
        #pragma unroll
        for (int c = 0; c < 32; ++c) red |= part[c * 32 + tid];
        uint32_t nk = vbs[tid] & ~red;
        uint64_t chg = __ballot(nk != Kvec[tid]);
        Kvec[tid] = nk;
        if (tid == 0) sflag = (chg != 0ull) ? 1u : 0u;
      }
      __syncthreads();
      go = sflag;
    }
  }

  // output: row already in registers (gathered before the spin)
  bool kept = (Kvec[tid >> 5] >> (tid & 31)) & 1u;
  float m = kept ? 1.0f : 0.0f;
  float score = __fmul_rn(r3.w, r1.x);   // == cls*obj, identical to reference path
  float hw = __fmul_rn(r0.z, 0.5f), hh = __fmul_rn(r0.w, 0.5f);
  float4 o0 = make_float4(__fsub_rn(r0.x, hw) * m, __fsub_rn(r0.y, hh) * m,
                          __fadd_rn(r0.x, hw) * m, __fadd_rn(r0.y, hh) * m);
  float4 o1 = make_float4(score * m, r1.y * m, r1.z * m, r1.w * m);
  float4 o2 = make_float4(r2.x * m, r2.y * m, r2.z * m, r2.w * m);
  float4 o3 = make_float4(r3.x * m, r3.y * m, r3.z * m, 0.0f);
  float4* dst = (float4*)(det + ((size_t)b * TOPK + tid) * NF);
  dst[0] = o0; dst[1] = o1; dst[2] = o2; dst[3] = o3;
  keep_out[(size_t)b * TOPK + tid] = m;
}

extern "C" void kernel_launch(void* const* d_in, const int* in_sizes, int n_in,
                              void* d_out, int out_size, void* d_ws, size_t ws_size,
                              hipStream_t stream) {
  const float* pred = (const float*)d_in[0];
  float* det = (float*)d_out;
  float* keep = det + (size_t)NB * TOPK * NF;

  uint8_t* ws = (uint8_t*)d_ws;
  size_t off = 0;
  uint32_t* keys = (uint32_t*)(ws + off); off += (size_t)NB * NN * 4;       // 3.2 MB
  uint32_t* mask = (uint32_t*)(ws + off); off += (size_t)NB * 32 * TOPK * 4;// 4 MB
  uint32_t* cnt = (uint32_t*)(ws + off);  off += (size_t)NB * CSTRIDE * 4;  // 4 KB

  k_keys<<<(NB * NN + 255) / 256, 256, 0, stream>>>(pred, keys, cnt);
  dim3 g(NB, 8);
  k_nms<<<g, 1024, 0, stream>>>(pred, keys, mask, cnt, det, keep);
}

// Round 16
// 141.702 us; speedup vs baseline: 1.1464x; 1.0081x over previous
//
#include <hip/hip_runtime.h>
#include <stdint.h>

#define NB 32
#define NN 25200
#define NN4 6300          // NN/4, exact
#define TOPK 1024
#define NF 16
#define CONF 0.25f
#define IOU_T 0.45f
#define NBIN 4096
#define CAP 2048
#define KEY_BASE 0xBE800001u  // lowest possible valid key (score just above 0.25)
#define PITCH 257             // uint4 row pitch in LDS (bank-spread, no swizzle)
#define CSTRIDE 32            // counter stride in uints = 128 B = one cache line

// monotone-ascending uint32 map of the reference's s = valid ? obj*cls : -1.0
// Valid entries (obj>CONF && score>CONF) map to keys >= KEY_BASE; all invalid
// entries (s=-1.0 -> 0x407FFFFF) land strictly below KEY_BASE.
__device__ __forceinline__ uint32_t score_key(float obj, float cls) {
  float score = __fmul_rn(cls, obj);
  bool valid = (obj > CONF) && (score > CONF);
  float s = valid ? score : -1.0f;
  uint32_t u = __float_as_uint(s);
  return (u & 0x80000000u) ? ~u : (u | 0x80000000u);
}

__device__ __forceinline__ uint64_t shfl_xor_u64(uint64_t v, int m) {
  uint32_t lo = __shfl_xor((uint32_t)v, m, 64);
  uint32_t hi = __shfl_xor((uint32_t)(v >> 32), m, 64);
  return ((uint64_t)hi << 32) | lo;
}

// Full-grid key compute — standalone on purpose (R15 structure matrix: deep
// 3150-block queue ≈ 9us BW-bound; in-kernel keys were latency-starved).
// Also zeroes the strided slab counters for k_nms.
__global__ void k_keys(const float* __restrict__ pred, uint32_t* __restrict__ keys,
                       uint32_t* __restrict__ cnt) {
  if (blockIdx.x == 0) {
    #pragma unroll
    for (int q = 0; q < 4; ++q) cnt[threadIdx.x + q * 256] = 0u;
  }
  int g = blockIdx.x * blockDim.x + threadIdx.x;
  if (g >= NB * NN) return;
  const float* row = pred + (size_t)g * NF;
  keys[g] = score_key(row[4], row[15]);
}

// R16 = R15 with the barrier-count fix (the ~27us "ghost" in every
// phase-chained kernel tracks the ~45 full-block barriers; the bitonic alone
// had 28):
//  (1) PING-PONG bitonic: each cross-wave stage is write -> ONE barrier ->
//      read, alternating two 16 KB buffers. Safety: a thread can only reach
//      stage s+2's write (same buffer as stage s) after passing stage s+1's
//      barrier, which requires every thread to have finished stage s's reads
//      -> no write-after-read hazard with 2 buffers. 28 -> 14 barriers.
//  (2) all 7 key uint4 loads prefetched before the histogram (6 guards are
//      compile-time true; k=6 clamped + contribution-guarded) -> 7 loads in
//      flight instead of serialized load->use rounds.
//  (3) hist zero via one uint4 store per thread.
// Everything else byte-identical to R15 (redundant select, pair-balanced
// mask, one strided-counter sync storm, Jacobi tail).
__global__ __launch_bounds__(1024, 4) void k_nms(const float* __restrict__ pred,
                                                 const uint32_t* __restrict__ keys,
                                                 uint32_t* __restrict__ mask,
                                                 uint32_t* __restrict__ cnt,
                                                 float* __restrict__ det,
                                                 float* __restrict__ keep_out) {
  int b = blockIdx.x;
  int sblk = blockIdx.y;
  int tid = threadIdx.x;
  int lane = tid & 63, wid = tid >> 6;
  int rg = tid & 31;
  int cc = tid >> 5;

  __shared__ uint4 sm4[32 * PITCH];      // 131.6 KB big buffer (stage target)
  __shared__ uint32_t part[1024];
  __shared__ uint32_t Kvec[32];
  __shared__ uint32_t vbs[32];
  __shared__ uint32_t sflag;
  __shared__ uint32_t wsum[16];
  __shared__ uint32_t sh_bin;
  __shared__ uint32_t sh_cnt;

  // disjoint carves inside sm4 (all dead before the stage overwrites them):
  float* bx1 = (float*)sm4;              // 5 x 4 KB box arrays   [0, 20K)
  float* by1 = bx1 + TOPK;
  float* bx2 = by1 + TOPK;
  float* by2 = bx2 + TOPK;
  float* bar = by2 + TOPK;
  uint32_t* hist = (uint32_t*)(bar + TOPK);   // 16 KB              [20K, 36K)
  uint64_t* entA = (uint64_t*)(hist + NBIN);  // 16 KB              [36K, 52K)
  uint64_t* entB = entA + CAP;                // 16 KB              [52K, 68K)

  uint32_t* cntm = cnt + (size_t)b * CSTRIDE;   // one cache line per image

  // ---- phase 1: select, run REDUNDANTLY by all 8 blocks of this image ----
  const uint4* kb4 = (const uint4*)(keys + (size_t)b * NN);
  {
    uint4 z = make_uint4(0u, 0u, 0u, 0u);
    *(uint4*)&hist[4 * tid] = z;
  }
  entA[tid] = 0; entA[tid + 1024] = 0;
  if (tid == 0) { sh_cnt = 0; sh_bin = 0; }
  __syncthreads();

  // prefetch ALL key loads, then histogram from registers
  uint4 kreg[7];
  #pragma unroll
  for (int k = 0; k < 6; ++k) kreg[k] = kb4[tid + k * 1024];  // i < 6144 < NN4 always
  kreg[6] = kb4[(tid + 6144 < NN4) ? (tid + 6144) : (NN4 - 1)];
  #pragma unroll
  for (int k = 0; k < 7; ++k) {
    int i = tid + k * 1024;
    if (i < NN4) {   // k<6: folds to true at compile time
      uint32_t kv[4] = {kreg[k].x, kreg[k].y, kreg[k].z, kreg[k].w};
      #pragma unroll
      for (int c = 0; c < 4; ++c) {
        uint32_t key = kv[c];
        if (key >= KEY_BASE) {
          uint32_t bin = (key - KEY_BASE) >> 12;
          if (bin > NBIN - 1) bin = NBIN - 1;
          atomicAdd(&hist[bin], 1u);
        }
      }
    }
  }
  __syncthreads();

  // descending-bin cumulative via shfl scan; find crossing bin
  uint32_t h[4]; uint32_t s = 0;
  #pragma unroll
  for (int k = 0; k < 4; ++k) { h[k] = hist[NBIN - 1 - (4 * tid + k)]; s += h[k]; }
  uint32_t my = s;
  #pragma unroll
  for (int d = 1; d < 64; d <<= 1) {
    uint32_t v = __shfl_up(s, d, 64);
    if (lane >= d) s += v;
  }
  if (lane == 63) wsum[wid] = s;
  __syncthreads();
  uint32_t base = 0;
  for (int w = 0; w < wid; ++w) base += wsum[w];
  uint32_t cum = base + s - my;  // exclusive prefix (descending bins)
  #pragma unroll
  for (int k = 0; k < 4; ++k) {
    if (cum < TOPK && cum + h[k] >= TOPK) sh_bin = (uint32_t)(NBIN - 1 - (4 * tid + k));
    cum += h[k];
  }
  __syncthreads();
  uint32_t thr = KEY_BASE + (sh_bin << 12);

  // compact from registers (no second global pass)
  #pragma unroll
  for (int k = 0; k < 7; ++k) {
    int i = tid + k * 1024;
    if (i < NN4) {
      uint32_t kv[4] = {kreg[k].x, kreg[k].y, kreg[k].z, kreg[k].w};
      #pragma unroll
      for (int c = 0; c < 4; ++c) {
        uint32_t key = kv[c];
        if (key >= thr) {
          uint32_t p = atomicAdd(&sh_cnt, 1u);
          if (p < CAP) entA[p] = ((uint64_t)key << 32) | (uint32_t)(~(uint32_t)(4 * i + c));
        }
      }
    }
  }
  __syncthreads();

  // register bitonic, 2048 descending, 2 elems/thread; PING-PONG LDS stages
  // (one barrier per cross-wave stage). Canonicalizes compaction arrival
  // order -> identical results across the 8 blocks of an image.
  uint64_t v0 = entA[tid], v1 = entA[tid + 1024];
  int pp = 0;   // 0: next LDS stage uses entB; 1: entA
  for (unsigned kk = 2; kk <= CAP; kk <<= 1) {
    for (unsigned j = kk >> 1; j > 0; j >>= 1) {
      if (j == 1024) {
        uint64_t mx = v0 > v1 ? v0 : v1;
        uint64_t mn = v0 > v1 ? v1 : v0;
        v0 = mx; v1 = mn;  // desc=true for kk=2048
      } else if (j >= 64) {
        uint64_t* buf = pp ? entA : entB;
        buf[tid] = v0; buf[tid + 1024] = v1;
        __syncthreads();
        uint64_t p0 = buf[tid ^ j], p1 = buf[(tid ^ j) + 1024];
        bool low = ((tid & j) == 0);
        bool d0 = ((tid & kk) == 0);
        bool d1 = (((tid + 1024) & kk) == 0);
        v0 = (low != d0) ? (v0 < p0 ? v0 : p0) : (v0 > p0 ? v0 : p0);
        v1 = (low != d1) ? (v1 < p1 ? v1 : p1) : (v1 > p1 ? v1 : p1);
        pp ^= 1;
      } else {
        uint64_t p0 = shfl_xor_u64(v0, (int)j);
        uint64_t p1 = shfl_xor_u64(v1, (int)j);
        bool low = ((tid & j) == 0);
        bool d0 = ((tid & kk) == 0);
        bool d1 = (((tid + 1024) & kk) == 0);
        v0 = (low != d0) ? (v0 < p0 ? v0 : p0) : (v0 > p0 ? v0 : p0);
        v1 = (low != d1) ? (v1 < p1 ? v1 : p1) : (v1 > p1 ? v1 : p1);
      }
    }
  }
  uint32_t key = (uint32_t)(v0 >> 32);
  uint32_t nn = ~(uint32_t)(v0 & 0xFFFFFFFFu);
  if (nn >= NN) nn = 0;  // zero-pad path
  int n = (int)nn;       // this rank's source row — stays in a register

  // validity ballot straight into LDS (used by the tail block only)
  {
    bool valid = key >= KEY_BASE;
    uint64_t bal = __ballot(valid);
    if (lane == 0) {
      vbs[2 * wid] = (uint32_t)bal;  vbs[2 * wid + 1] = (uint32_t)(bal >> 32);
      Kvec[2 * wid] = (uint32_t)bal; Kvec[2 * wid + 1] = (uint32_t)(bal >> 32);
    }
  }

  // boxes: one scattered gather into LOCAL LDS (no global round-trip)
  {
    const float4* row = (const float4*)(pred + ((size_t)b * NN + n) * NF);
    float4 r0 = row[0];
    float hw = __fmul_rn(r0.z, 0.5f), hh = __fmul_rn(r0.w, 0.5f);
    float x1 = __fsub_rn(r0.x, hw), y1 = __fsub_rn(r0.y, hh);
    float x2 = __fadd_rn(r0.x, hw), y2 = __fadd_rn(r0.y, hh);
    bx1[tid] = x1; by1[tid] = y1; bx2[tid] = x2; by2[tid] = y2;
    bar[tid] = __fmul_rn(__fsub_rn(x2, x1), __fsub_rn(y2, y1));
  }
  __syncthreads();

  // ---- phase 2: mask, pair-balanced coalesced mapping (R14) ----
  // quad index: rg<16 -> q = 32*sblk + rg ; rg>=16 -> q = 32*(7-sblk) + rg.
  // Active-word sum per block = 528 for every s (exact balance), and each
  // 16-lane group stores a contiguous 256-B segment (coalesced).
  int q = (rg < 16) ? (32 * sblk + rg) : (32 * (7 - sblk) + rg);
  int i0 = 4 * q;                 // rows i0..i0+3, all in word iw
  int iw = q >> 3;
  uint32_t wreg[4] = {0u, 0u, 0u, 0u};
  if (cc >= iw) {
    float rx1[4], ry1[4], rx2[4], ry2[4], rar[4];
    #pragma unroll
    for (int k = 0; k < 4; ++k) {
      rx1[k] = bx1[i0 + k]; ry1[k] = by1[i0 + k];
      rx2[k] = bx2[i0 + k]; ry2[k] = by2[i0 + k]; rar[k] = bar[i0 + k];
    }
    for (int jj = 0; jj < 32; ++jj) {
      int j = cc * 32 + jj;
      float cx1 = bx1[j], cy1 = by1[j], cx2 = bx2[j], cy2 = by2[j], car = bar[j];
      #pragma unroll
      for (int k = 0; k < 4; ++k) {
        float lx = fmaxf(rx1[k], cx1);
        float ly = fmaxf(ry1[k], cy1);
        float rx = fminf(rx2[k], cx2);
        float ry = fminf(ry2[k], cy2);
        float wd = fmaxf(__fsub_rn(rx, lx), 0.0f);
        float ht = fmaxf(__fsub_rn(ry, ly), 0.0f);
        float inter = __fmul_rn(wd, ht);
        float den = __fadd_rn(__fsub_rn(__fadd_rn(rar[k], car), inter), 1e-7f);
        float iou = __fdiv_rn(inter, den);
        wreg[k] |= (iou > IOU_T ? 1u : 0u) << jj;
      }
    }
    if (cc == iw) {
      #pragma unroll
      for (int k = 0; k < 4; ++k)
        wreg[k] &= ~((2u << ((i0 + k) & 31)) - 1u);  // keep only j > i (strict)
    }
  }
  {
    uint4 out = make_uint4(wreg[0], wreg[1], wreg[2], wreg[3]);
    *(uint4*)&mask[((size_t)b * 32 + cc) * TOPK + i0] = out;
  }
  __syncthreads();   // drain mask stores
  if (tid == 0)
    __hip_atomic_fetch_add(cntm, 1u, __ATOMIC_RELEASE, __HIP_MEMORY_SCOPE_AGENT);
  if (sblk != 0) return;

  // ---- phase 3 (sblk==0): early-gather, wait, stage, Jacobi, output ----
  const float4* rowv = (const float4*)(pred + ((size_t)b * NN + n) * NF);
  float4 r0 = rowv[0], r1 = rowv[1], r2 = rowv[2], r3 = rowv[3];

  if (tid == 0) {
    while (__hip_atomic_load(cntm, __ATOMIC_RELAXED, __HIP_MEMORY_SCOPE_AGENT) < 8u)
      __builtin_amdgcn_s_sleep(16);
    (void)__hip_atomic_load(cntm, __ATOMIC_ACQUIRE, __HIP_MEMORY_SCOPE_AGENT);
  }
  __syncthreads();

  // bulk stage: 128 KiB coalesced into pitch-257 LDS rows
  const uint4* gm4 = (const uint4*)(mask + (size_t)b * (32 * TOPK));
  #pragma unroll
  for (int qq = 0; qq < 8; ++qq) {
    int idx4 = tid + qq * 1024;         // uint4 index 0..8191
    int row = idx4 >> 8;                // 256 uint4 per mask word-row
    int col4 = idx4 & 255;
    sm4[row * PITCH + col4] = gm4[idx4];
  }
  __syncthreads();

  // Jacobi sweeps: K <- vb & ~S^T K until fixpoint (== exact greedy keep;
  // uniqueness by induction on smallest index — R10 derivation).
  {
    int l = tid & 31;                    // mask word this thread accumulates
    int chunk = tid >> 5;                // row block chunk*32..chunk*32+31
    const int rbase = l * PITCH + chunk * 8;
    uint32_t go = 1u;
    for (int sweep = 0; sweep < 1030 && go; ++sweep) {
      uint32_t kc = Kvec[chunk];         // kept bits for this row block
      uint32_t acc = 0;
      #pragma unroll
      for (int qq = 0; qq < 8; ++qq) {
        uint4 v = sm4[rbase + qq];
        acc |= (0u - ((kc >> (qq * 4 + 0)) & 1u)) & v.x;
        acc |= (0u - ((kc >> (qq * 4 + 1)) & 1u)) & v.y;
        acc |= (0u - ((kc >> (qq * 4 + 2)) & 1u)) & v.z;
        acc |= (0u - ((kc >> (qq * 4 + 3)) & 1u)) & v.w;
      }
      part[tid] = acc;
      __syncthreads();
      if (tid < 32) {
        uint32_t red = 0;
        #pragma unroll
        for (int c = 0; c < 32; ++c) red |= part[c * 32 + tid];
        uint32_t nk = vbs[tid] & ~red;
        uint64_t chg = __ballot(nk != Kvec[tid]);
        Kvec[tid] = nk;
        if (tid == 0) sflag = (chg != 0ull) ? 1u : 0u;
      }
      __syncthreads();
      go = sflag;
    }
  }

  // output: row already in registers (gathered before the spin)
  bool kept = (Kvec[tid >> 5] >> (tid & 31)) & 1u;
  float m = kept ? 1.0f : 0.0f;
  float score = __fmul_rn(r3.w, r1.x);   // == cls*obj, identical to reference path
  float hw = __fmul_rn(r0.z, 0.5f), hh = __fmul_rn(r0.w, 0.5f);
  float4 o0 = make_float4(__fsub_rn(r0.x, hw) * m, __fsub_rn(r0.y, hh) * m,
                          __fadd_rn(r0.x, hw) * m, __fadd_rn(r0.y, hh) * m);
  float4 o1 = make_float4(score * m, r1.y * m, r1.z * m, r1.w * m);
  float4 o2 = make_float4(r2.x * m, r2.y * m, r2.z * m, r2.w * m);
  float4 o3 = make_float4(r3.x * m, r3.y * m, r3.z * m, 0.0f);
  float4* dst = (float4*)(det + ((size_t)b * TOPK + tid) * NF);
  dst[0] = o0; dst[1] = o1; dst[2] = o2; dst[3] = o3;
  keep_out[(size_t)b * TOPK + tid] = m;
}

extern "C" void kernel_launch(void* const* d_in, const int* in_sizes, int n_in,
                              void* d_out, int out_size, void* d_ws, size_t ws_size,
                              hipStream_t stream) {
  const float* pred = (const float*)d_in[0];
  float* det = (float*)d_out;
  float* keep = det + (size_t)NB * TOPK * NF;

  uint8_t* ws = (uint8_t*)d_ws;
  size_t off = 0;
  uint32_t* keys = (uint32_t*)(ws + off); off += (size_t)NB * NN * 4;       // 3.2 MB
  uint32_t* mask = (uint32_t*)(ws + off); off += (size_t)NB * 32 * TOPK * 4;// 4 MB
  uint32_t* cnt = (uint32_t*)(ws + off);  off += (size_t)NB * CSTRIDE * 4;  // 4 KB

  k_keys<<<(NB * NN + 255) / 256, 256, 0, stream>>>(pred, keys, cnt);
  dim3 g(NB, 8);
  k_nms<<<g, 1024, 0, stream>>>(pred, keys, mask, cnt, det, keep);
}